// Round 1
// baseline (546.631 us; speedup 1.0000x reference)
//
#include <hip/hip_runtime.h>

// GraphAttentionEmbedding: 2x TransformerConv (PyG) on MI355X (gfx950).
// N=50000, E=400000, IN=128, H1=8*16=128, OUT=128, EDIM=32.
// PROVEN: fp32 inputs (runtime-detected), fp32 output; internal bf16+fp32 acc.
// R14 baseline: 456.8us. attn FETCH == compulsory bytes; 2/3 of it was the
// materialized ee stream (256B/edge) + gemm_ee's 205MB of writes.
// R15: ee-factorization.
//   score: q.ee = (x @ Wqe + bqe) . ef   (Wqe[i,(h,d)] = sum_c Wq[i,16h+c]*We[d,16h+c])
//   value: sum_e w*ee = (sum_e w*ef) @ We  (32-wide F per (node,head), LDS epilogue)
// -> gemm_ee eliminated; attn per-edge stream 256B -> 64B (efg bf16, CSR order,
//    shared by both layers); qWe rides the existing node-GEMM (extra sets).

using u16 = unsigned short;
using u32 = unsigned int;

#define NODES 50000
#define EDGES 400000
#define NB196 196   // ceil(50000/256)

typedef __attribute__((ext_vector_type(8))) short bf16x8;
typedef __attribute__((ext_vector_type(4))) float f32x4;

__device__ __forceinline__ float bflo(u32 u) { return __uint_as_float(u << 16); }
__device__ __forceinline__ float bfhi(u32 u) { return __uint_as_float(u & 0xffff0000u); }
__device__ __forceinline__ u16 f2bf(float f) {
    u32 u = __float_as_uint(f);
    u += 0x7fffu + ((u >> 16) & 1u);   // RNE
    return (u16)(u >> 16);
}
__device__ __forceinline__ u32 pack2(float a, float b) {
    return (u32)f2bf(a) | ((u32)f2bf(b) << 16);
}
__device__ __forceinline__ float rdv(const void* p, int i, int f) {
    return f ? ((const float*)p)[i]
             : __uint_as_float(((u32) reinterpret_cast<const u16*>(p)[i]) << 16);
}

// DPP lane-add at VALU speed (no DS pipe).
template <int CTRL>
__device__ __forceinline__ float dpp_addf(float x) {
    int y = __builtin_amdgcn_update_dpp(0, __float_as_int(x), CTRL, 0xF, 0xF, true);
    return x + __int_as_float(y);
}
template <int GRP>
__device__ __forceinline__ float grp_sum(float p, int lane) {
    p = dpp_addf<0xB1>(p);    // xor 1
    p = dpp_addf<0x4E>(p);    // xor 2
    p = dpp_addf<0x141>(p);   // xor 4 (8-group done)
    if (GRP == 64) {
        p = dpp_addf<0x140>(p);   // xor 8
        p += __int_as_float(__builtin_amdgcn_ds_swizzle(__float_as_int(p), 0x401F)); // xor16
        p += __int_as_float(__builtin_amdgcn_ds_bpermute((lane ^ 32) << 2,
                                                         __float_as_int(p)));        // xor32
    }
    return p;
}

// ---------------- diagnostic sentinel (fp32 out) ----------------------------
__global__ __launch_bounds__(256) void fill_sentinel(float* __restrict__ out, int n, float val) {
    int i = blockIdx.x * 256 + threadIdx.x;
    if (i < n) out[i] = val;
}

// ---------------- runtime format detection (one wave) -----------------------
__global__ __launch_bounds__(64) void detect_fmt(const u32* __restrict__ xw,
                                                 const int* __restrict__ eraw,
                                                 int* __restrict__ flags) {
    int lane = threadIdx.x;
    u32 e = (xw[lane] >> 7) & 0xffu;
    unsigned long long sane = __ballot(e >= 90u && e <= 141u);
    unsigned long long zodd = __ballot(eraw[1 + 2 * lane] == 0);
    if (lane == 0) {
        flags[0] = (sane == ~0ull) ? 0 : 1;   // 1 = fp32
        flags[1] = (zodd == ~0ull) ? 1 : 0;   // 1 = int64
    }
}

// ---------------- x -> bf16 conversion (once) -------------------------------
__global__ __launch_bounds__(256) void convert_x(const void* __restrict__ X,
                                                 const int* __restrict__ flags,
                                                 u16* __restrict__ xbf, int total) {
    int i = (blockIdx.x * 256 + threadIdx.x) * 8;
    if (i >= total) return;
    if (flags[0]) {
        const float* xf = (const float*)X + i;
        float4 lo = *reinterpret_cast<const float4*>(xf);
        float4 hi = *reinterpret_cast<const float4*>(xf + 4);
        uint4 val = make_uint4(pack2(lo.x, lo.y), pack2(lo.z, lo.w),
                               pack2(hi.x, hi.y), pack2(hi.z, hi.w));
        *reinterpret_cast<uint4*>(xbf + i) = val;
    } else {
        *reinterpret_cast<uint4*>(xbf + i) =
            *reinterpret_cast<const uint4*>((const u16*)X + i);
    }
}

// ---------------- weight transpose+convert: W[K][128] -> Wt[128][K] bf16 ----
struct TPtrs {
    const void* src[8];
    u16*        dst[8];
    int         K[8];
};

__global__ __launch_bounds__(256) void transpose_w(TPtrs P, const int* __restrict__ fmt) {
    int m = blockIdx.x;
    int f = *fmt;
    int K = P.K[m];
    int quarter = (K * 128) >> 2;
    u16* d = P.dst[m];
    int base = blockIdx.y * quarter;
    const float* sf = (const float*)P.src[m];
    const u16*   sb = (const u16*)P.src[m];
    for (int idx = base + threadIdx.x; idx < base + quarter; idx += 256) {
        int k = idx >> 7, n = idx & 127;
        d[n * K + k] = f ? f2bf(sf[idx]) : sb[idx];
    }
}

// ---------------- combined weights: Wqe = Wq (.) We per head ----------------
// L1: Wqe1[i, h*32+d] = sum_{c<16} Wq1[i,16h+c]*We1[d,16h+c]  (h=0..7)
//     -> Wt format split: WtA (cols 0..127 = h<4), WtB (h>=4).
// L2: Wqe2[i, d] = sum_{c<128} Wq2[i,c]*We2[d,c]  (d=0..31; cols 32..127 = 0)
// biases: bqe1[256], bqe2[128] (fp32).
struct WqeP {
    const void *Wq1, *We1, *bq1, *Wq2, *We2, *bq2;
    u16 *WtA, *WtB, *Wt2;
    float *bqe1, *bqe2;
};

__global__ __launch_bounds__(256) void make_wqe(WqeP P, const int* __restrict__ flags) {
    int f = flags[0];
    int idx = blockIdx.x * 256 + threadIdx.x;
    if (idx < 32768) {                          // layer-1 weights
        int col = idx >> 7, i = idx & 127;
        int hh = col >> 5, d = col & 31;
        float s = 0.f;
#pragma unroll
        for (int c = 0; c < 16; ++c)
            s += rdv(P.Wq1, i * 128 + hh * 16 + c, f) * rdv(P.We1, d * 128 + hh * 16 + c, f);
        if (col < 128) P.WtA[col * 128 + i] = f2bf(s);
        else           P.WtB[(col - 128) * 128 + i] = f2bf(s);
    } else if (idx < 49152) {                   // layer-2 weights (zero-padded)
        int t = idx - 32768;
        int col = t >> 7, i = t & 127;
        float s = 0.f;
        if (col < 32) {
            for (int c = 0; c < 128; ++c)
                s += rdv(P.Wq2, i * 128 + c, f) * rdv(P.We2, col * 128 + c, f);
        }
        P.Wt2[col * 128 + i] = f2bf(s);
    } else if (idx < 49408) {                   // bqe1
        int col = idx - 49152;
        int hh = col >> 5, d = col & 31;
        float s = 0.f;
#pragma unroll
        for (int c = 0; c < 16; ++c)
            s += rdv(P.bq1, hh * 16 + c, f) * rdv(P.We1, d * 128 + hh * 16 + c, f);
        P.bqe1[col] = s;
    } else if (idx < 49536) {                   // bqe2
        int d = idx - 49408;
        float s = 0.f;
        if (d < 32)
            for (int c = 0; c < 128; ++c)
                s += rdv(P.bq2, c, f) * rdv(P.We2, d * 128 + c, f);
        P.bqe2[d] = s;
    }
}

// ---------------- CSR build (by dst) ----------------------------------------
__global__ __launch_bounds__(256) void count_deg(const int* __restrict__ raw,
                                                 const int* __restrict__ flags,
                                                 int* __restrict__ deg, int E) {
    int e = blockIdx.x * 256 + threadIdx.x;
    if (e < E) {
        int f = flags[1];
        int d = f ? raw[2 * (E + e)] : raw[E + e];
        if ((unsigned)d < (unsigned)NODES) atomicAdd(&deg[d], 1);
    }
}

__device__ __forceinline__ int block_scan256(int v) {
    __shared__ int ws[4];
    int t = threadIdx.x, lane = t & 63, w = t >> 6;
    int x = v;
#pragma unroll
    for (int off = 1; off < 64; off <<= 1) {
        int y = __shfl_up(x, off, 64);
        if (lane >= off) x += y;
    }
    if (lane == 63) ws[w] = x;
    __syncthreads();
#pragma unroll
    for (int j = 0; j < 3; ++j)
        if (j < w) x += ws[j];
    return x;
}

__global__ __launch_bounds__(256) void scan_a(const int* __restrict__ deg,
                                              int* __restrict__ bsum, int n) {
    int i = blockIdx.x * 256 + threadIdx.x;
    int v = (i < n) ? deg[i] : 0;
    int incl = block_scan256(v);
    if (threadIdx.x == 255) bsum[blockIdx.x] = incl;
}

__global__ __launch_bounds__(256) void scan_b(int* __restrict__ bsum, int nb) {
    int t = threadIdx.x;
    int v = (t < nb) ? bsum[t] : 0;
    int incl = block_scan256(v);
    if (t < nb) bsum[t] = incl - v;
}

__global__ __launch_bounds__(256) void scan_c(const int* __restrict__ deg,
                                              const int* __restrict__ bsum,
                                              int* __restrict__ row_ptr,
                                              int* __restrict__ cursor, int n) {
    int b = blockIdx.x;
    int i = b * 256 + threadIdx.x;
    int v = (i < n) ? deg[i] : 0;
    int incl = block_scan256(v) + bsum[b];
    if (i < n) {
        row_ptr[i + 1] = incl;
        cursor[i] = incl - v;
    }
    if (i == 0) row_ptr[0] = 0;
}

__global__ __launch_bounds__(256) void fill_csr(const int* __restrict__ raw,
                                                const int* __restrict__ flags,
                                                int* __restrict__ cursor,
                                                int* __restrict__ srcs,
                                                int* __restrict__ eids, int E) {
    int e = blockIdx.x * 256 + threadIdx.x;
    if (e < E) {
        int f = flags[1];
        int d = f ? raw[2 * (E + e)] : raw[E + e];
        int s = f ? raw[2 * e] : raw[e];
        if ((unsigned)d < (unsigned)NODES && (unsigned)s < (unsigned)NODES) {
            int pos = atomicAdd(&cursor[d], 1);
            if ((unsigned)pos < (unsigned)E) { srcs[pos] = s; eids[pos] = e; }
        }
    }
}

// ---------------- ef gather to CSR order, bf16 (shared by both layers) ------
__global__ __launch_bounds__(256) void gather_ef(const int* __restrict__ eids,
                                                 const void* __restrict__ EF,
                                                 const int* __restrict__ flags,
                                                 u16* __restrict__ EFG, int E) {
    int t = blockIdx.x * 256 + threadIdx.x;
    int pos = t >> 2, seg = t & 3;
    if (pos >= E) return;
    int e = eids[pos];
    uint4 val;
    if (flags[0]) {
        const float* src = (const float*)EF + (size_t)e * 32 + seg * 8;
        float4 lo = *reinterpret_cast<const float4*>(src);
        float4 hi = *reinterpret_cast<const float4*>(src + 4);
        val = make_uint4(pack2(lo.x, lo.y), pack2(lo.z, lo.w),
                         pack2(hi.x, hi.y), pack2(hi.z, hi.w));
    } else {
        val = *reinterpret_cast<const uint4*>((const u16*)EF + (size_t)e * 32 + seg * 8);
    }
    *reinterpret_cast<uint4*>(EFG + (size_t)pos * 32 + seg * 8) = val;
}

// ---------------- GEMM: O[M,128] = A[M,128] @ Wt[128,128]^T + bias ----------
// LDS-staged A (bf16, pre-converted) + B; one weight set per block (grid.y).
// Operand-swapped MFMA: lane acc[nt] = 4 consecutive out-cols of one row
// -> epilogue is 8 coalesced uint2 stores (verified R13/R14).
struct GemmSets {
    const u16*  Wt[6];
    const void* bias[6];
    u16*        O[6];
    int         bf32[6];   // 1 = bias is fp32 always, 0 = follow input flags
};

__global__ __launch_bounds__(256) void gemm128(
    const u16* __restrict__ A, const int* __restrict__ flags, GemmSets S, int M) {
    constexpr int K = 128;
    constexpr int PAD = K + 8;
    constexpr int KV = K / 8;
    __shared__ u16 Asl[64 * PAD];
    __shared__ u16 Bsl[128 * PAD];

    const u16*  Wt   = S.Wt[blockIdx.y];
    const void* bias = S.bias[blockIdx.y];
    u16*        O    = S.O[blockIdx.y];
    int f = S.bf32[blockIdx.y] ? 1 : flags[0];
    int m0 = blockIdx.x * 64;

    for (int idx = threadIdx.x; idx < 64 * KV; idx += 256) {
        int r = idx / KV, cv = idx % KV;
        int gr = m0 + r;
        uint4 val = make_uint4(0, 0, 0, 0);
        if (gr < M) val = *reinterpret_cast<const uint4*>(A + (size_t)gr * K + cv * 8);
        *reinterpret_cast<uint4*>(&Asl[r * PAD + cv * 8]) = val;
    }
    for (int idx = threadIdx.x; idx < 128 * KV; idx += 256) {
        int r = idx / KV, cv = idx % KV;
        *reinterpret_cast<uint4*>(&Bsl[r * PAD + cv * 8]) =
            *reinterpret_cast<const uint4*>(Wt + r * K + cv * 8);
    }
    __syncthreads();

    int lane = threadIdx.x & 63, wv = threadIdx.x >> 6;
    int l15 = lane & 15;
    int quad = lane >> 4;
    int kq = quad * 8;

    f32x4 b4[8];
#pragma unroll
    for (int nt = 0; nt < 8; ++nt) {
        int col0 = nt * 16 + quad * 4;
        if (bias) {
            if (f) {
                b4[nt] = *reinterpret_cast<const f32x4*>((const float*)bias + col0);
            } else {
                uint2 bu = *reinterpret_cast<const uint2*>((const u16*)bias + col0);
                b4[nt][0] = bflo(bu.x); b4[nt][1] = bfhi(bu.x);
                b4[nt][2] = bflo(bu.y); b4[nt][3] = bfhi(bu.y);
            }
        } else {
            b4[nt][0] = b4[nt][1] = b4[nt][2] = b4[nt][3] = 0.f;
        }
    }

    f32x4 acc[8] = {};
#pragma unroll
    for (int k0 = 0; k0 < K; k0 += 32) {
        bf16x8 xf = *reinterpret_cast<const bf16x8*>(&Asl[(wv * 16 + l15) * PAD + k0 + kq]);
#pragma unroll
        for (int nt = 0; nt < 8; ++nt) {
            bf16x8 wf = *reinterpret_cast<const bf16x8*>(&Bsl[(nt * 16 + l15) * PAD + k0 + kq]);
            acc[nt] = __builtin_amdgcn_mfma_f32_16x16x32_bf16(wf, xf, acc[nt], 0, 0, 0);
        }
    }

    int row = m0 + wv * 16 + l15;
    if (row < M) {
        u16* Orow = O + (size_t)row * 128;
#pragma unroll
        for (int nt = 0; nt < 8; ++nt) {
            uint2 pk;
            pk.x = pack2(acc[nt][0] + b4[nt][0], acc[nt][1] + b4[nt][1]);
            pk.y = pack2(acc[nt][2] + b4[nt][2], acc[nt][3] + b4[nt][3]);
            *reinterpret_cast<uint2*>(Orow + nt * 16 + quad * 4) = pk;
        }
    }
}

// ---------------- attention: factorized ee, DPP, 8-batches ------------------
// Per wave = one dst node; lane (h=lane>>3, j=lane&7) owns channels 16h+2j..+1
// and ef dims 4j..4j+3. Score: p = q.k + qw.ef (group-summed). Value: a += w*v,
// F[4j..] += w*ef; per-node epilogue applies F @ We from LDS-staged We.
template <int HEADS, int F32OUT>
__global__ __launch_bounds__(256) void attn_kernel(
    const int* __restrict__ row_ptr, const int* __restrict__ srcs,
    const u16* __restrict__ Q, const u16* __restrict__ Kn,
    const u16* __restrict__ Vn, const u16* __restrict__ EFG,
    const u16* __restrict__ QWA, const u16* __restrict__ QWB,
    const u16* __restrict__ SK, const void* __restrict__ We,
    const int* __restrict__ flags, void* __restrict__ OUT, int nn) {
    __shared__ u32 WeLds[32 * 64];       // [d][chan-pair] packed bf16x2
    __shared__ float Flds[4][8][36];     // [wave][head][d] (+4 pad)

    int fmt = flags[0];
    for (int t = threadIdx.x; t < 2048; t += 256) {
        int d = t >> 6, l = t & 63;
        u32 val;
        if (fmt) {
            const float* wp = (const float*)We + d * 128 + 2 * l;
            val = pack2(wp[0], wp[1]);
        } else {
            val = *reinterpret_cast<const u32*>((const u16*)We + d * 128 + 2 * l);
        }
        WeLds[t] = val;
    }
    __syncthreads();

    int wv = threadIdx.x >> 6, lane = threadIdx.x & 63;
    int node = blockIdx.x * 4 + wv;
    if (node >= nn) return;
    int h = lane >> 3, j = lane & 7;
    int c0 = lane * 2;

    const float scale = (HEADS == 8) ? 0.25f : 0.08838834764831845f;  // 1/sqrt(C)
    const float escale = (HEADS == 8) ? scale : scale * 0.125f;       // /8 replicas
    constexpr int GRP = (HEADS == 8) ? 8 : 64;

    u32 qb = *reinterpret_cast<const u32*>(Q + (size_t)node * 128 + c0);
    float q0 = bflo(qb) * scale, q1 = bfhi(qb) * scale;

    const u16* qp = (HEADS == 8)
        ? ((h < 4 ? QWA : QWB) + (size_t)node * 128 + (h & 3) * 32 + j * 4)
        : (QWA + (size_t)node * 128 + j * 4);
    uint2 qwu = *reinterpret_cast<const uint2*>(qp);
    float qw0 = bflo(qwu.x) * escale, qw1 = bfhi(qwu.x) * escale;
    float qw2 = bflo(qwu.y) * escale, qw3 = bfhi(qwu.y) * escale;

    int beg = row_ptr[node], end = row_ptr[node + 1];
    float l_run = 0.f, a0 = 0.f, a1 = 0.f;
    float f0 = 0.f, f1 = 0.f, f2 = 0.f, f3 = 0.f;

    const u16* efp = EFG + j * 4;

    auto edge_step = [&](u32 kbv, u32 vbv, uint2 ebv) {
        float e0 = bflo(ebv.x), e1 = bfhi(ebv.x);
        float e2 = bflo(ebv.y), e3 = bfhi(ebv.y);
        float p = q0 * bflo(kbv);
        p = fmaf(q1, bfhi(kbv), p);
        p = fmaf(qw0, e0, p); p = fmaf(qw1, e1, p);
        p = fmaf(qw2, e2, p); p = fmaf(qw3, e3, p);
        p = grp_sum<GRP>(p, lane);
        float w = __expf(p);
        l_run += w;
        a0 = fmaf(w, bflo(vbv), a0);
        a1 = fmaf(w, bfhi(vbv), a1);
        f0 = fmaf(w, e0, f0); f1 = fmaf(w, e1, f1);
        f2 = fmaf(w, e2, f2); f3 = fmaf(w, e3, f3);
    };

    int i = beg;
    for (; i + 8 <= end; i += 8) {
        int sA[8];
#pragma unroll
        for (int t = 0; t < 8; ++t) sA[t] = srcs[i + t];
        u32 kb[8], vb[8]; uint2 eb[8];
#pragma unroll
        for (int t = 0; t < 8; ++t) {
            kb[t] = *reinterpret_cast<const u32*>(Kn + (size_t)sA[t] * 128 + c0);
            vb[t] = *reinterpret_cast<const u32*>(Vn + (size_t)sA[t] * 128 + c0);
            eb[t] = *reinterpret_cast<const uint2*>(efp + (size_t)(i + t) * 32);
        }
#pragma unroll
        for (int t = 0; t < 8; ++t) edge_step(kb[t], vb[t], eb[t]);
    }
    for (; i < end; ++i) {
        int s = srcs[i];
        u32 kbv = *reinterpret_cast<const u32*>(Kn + (size_t)s * 128 + c0);
        u32 vbv = *reinterpret_cast<const u32*>(Vn + (size_t)s * 128 + c0);
        uint2 ebv = *reinterpret_cast<const uint2*>(efp + (size_t)i * 32);
        edge_step(kbv, vbv, ebv);
    }

    // ---- per-node epilogue: out_ee[c] = sum_d F[h][d] * We[d][c] ----
    *reinterpret_cast<float4*>(&Flds[wv][h][4 * j]) = make_float4(f0, f1, f2, f3);
    float acc0 = 0.f, acc1 = 0.f;
#pragma unroll
    for (int d = 0; d < 32; ++d) {
        float Fd = Flds[wv][h][d];
        u32 we = WeLds[d * 64 + lane];
        acc0 = fmaf(Fd, bflo(we), acc0);
        acc1 = fmaf(Fd, bfhi(we), acc1);
    }

    float inv = 1.f / fmaxf(l_run, 1e-16f);
    u32 sb = *reinterpret_cast<const u32*>(SK + (size_t)node * 128 + c0);
    float o0 = fmaxf(fmaf(a0 + acc0, inv, bflo(sb)), 0.f);
    float o1 = fmaxf(fmaf(a1 + acc1, inv, bfhi(sb)), 0.f);
    if (F32OUT) {
        *reinterpret_cast<float2*>((float*)OUT + (size_t)node * 128 + c0) = make_float2(o0, o1);
    } else {
        *reinterpret_cast<u32*>((u16*)OUT + (size_t)node * 128 + c0) = pack2(o0, o1);
    }
}

// ---------------------------------------------------------------------------
extern "C" void kernel_launch(void* const* d_in, const int* in_sizes, int n_in,
                              void* d_out, int out_size, void* d_ws, size_t ws_size,
                              hipStream_t stream) {
    const int N = NODES, E = EDGES;
    const void* x  = d_in[0];
    const int*  ei = (const int*)d_in[1];
    const void* ef = d_in[2];
    const void* Wq1 = d_in[3];  const void* bq1 = d_in[4];
    const void* Wk1 = d_in[5];  const void* bk1 = d_in[6];
    const void* Wv1 = d_in[7];  const void* bv1 = d_in[8];
    const void* We1 = d_in[9];
    const void* Ws1 = d_in[10]; const void* bs1 = d_in[11];
    const void* Wq2 = d_in[12]; const void* bq2 = d_in[13];
    const void* Wk2 = d_in[14]; const void* bk2 = d_in[15];
    const void* Wv2 = d_in[16]; const void* bv2 = d_in[17];
    const void* We2 = d_in[18];
    const void* Ws2 = d_in[19]; const void* bs2 = d_in[20];

    char* ws = (char*)d_ws;
    size_t off = 0;
    auto carve = [&](size_t bytes) -> void* {
        void* p = ws + off;
        off += (bytes + 255) & ~(size_t)255;
        return p;
    };

    u16* WtQ1 = (u16*)carve(128 * 128 * 2);
    u16* WtK1 = (u16*)carve(128 * 128 * 2);
    u16* WtV1 = (u16*)carve(128 * 128 * 2);
    u16* WtS1 = (u16*)carve(128 * 128 * 2);
    u16* WtQ2 = (u16*)carve(128 * 128 * 2);
    u16* WtK2 = (u16*)carve(128 * 128 * 2);
    u16* WtV2 = (u16*)carve(128 * 128 * 2);
    u16* WtS2 = (u16*)carve(128 * 128 * 2);
    u16* WtqA = (u16*)carve(128 * 128 * 2);
    u16* WtqB = (u16*)carve(128 * 128 * 2);
    u16* Wtq2 = (u16*)carve(128 * 128 * 2);
    float* bqe1 = (float*)carve(256 * 4);
    float* bqe2 = (float*)carve(128 * 4);
    int* flags   = (int*)carve(256);
    int* deg     = (int*)carve((size_t)N * 4);
    int* bsum    = (int*)carve((size_t)NB196 * 4);
    int* row_ptr = (int*)carve((size_t)(N + 1) * 4);
    int* cursor  = (int*)carve((size_t)N * 4);
    int* srcs    = (int*)carve((size_t)E * 4);
    int* eids    = (int*)carve((size_t)E * 4);
    u16* xbf  = (u16*)carve((size_t)N * 128 * 2);
    u16* q    = (u16*)carve((size_t)N * 128 * 2);
    u16* k    = (u16*)carve((size_t)N * 128 * 2);
    u16* v    = (u16*)carve((size_t)N * 128 * 2);
    u16* sk   = (u16*)carve((size_t)N * 128 * 2);
    u16* h    = (u16*)carve((size_t)N * 128 * 2);
    u16* qweA = (u16*)carve((size_t)N * 128 * 2);
    u16* qweB = (u16*)carve((size_t)N * 128 * 2);
    u16* qwe2 = (u16*)carve((size_t)N * 128 * 2);
    u16* efg  = (u16*)carve((size_t)E * 32 * 2);
    const size_t REQ = off;   // ~146 MB (old path needed >=184 MB, so this fits)

    if (ws_size < REQ) {
        hipLaunchKernelGGL(fill_sentinel, dim3((out_size + 255) / 256), dim3(256), 0, stream,
                           (float*)d_out, out_size, 16.0f * (float)(ws_size >> 20));
        return;
    }

    hipLaunchKernelGGL(detect_fmt, dim3(1), dim3(64), 0, stream, (const u32*)x, ei, flags);

    hipLaunchKernelGGL(convert_x, dim3((N * 128 / 8 + 255) / 256), dim3(256), 0, stream,
                       x, flags, xbf, N * 128);

    TPtrs tp;
    tp.src[0] = Wq1; tp.dst[0] = WtQ1; tp.K[0] = 128;
    tp.src[1] = Wk1; tp.dst[1] = WtK1; tp.K[1] = 128;
    tp.src[2] = Wv1; tp.dst[2] = WtV1; tp.K[2] = 128;
    tp.src[3] = Ws1; tp.dst[3] = WtS1; tp.K[3] = 128;
    tp.src[4] = Wq2; tp.dst[4] = WtQ2; tp.K[4] = 128;
    tp.src[5] = Wk2; tp.dst[5] = WtK2; tp.K[5] = 128;
    tp.src[6] = Wv2; tp.dst[6] = WtV2; tp.K[6] = 128;
    tp.src[7] = Ws2; tp.dst[7] = WtS2; tp.K[7] = 128;
    hipLaunchKernelGGL(transpose_w, dim3(8, 4), dim3(256), 0, stream, tp, flags);

    WqeP wp;
    wp.Wq1 = Wq1; wp.We1 = We1; wp.bq1 = bq1;
    wp.Wq2 = Wq2; wp.We2 = We2; wp.bq2 = bq2;
    wp.WtA = WtqA; wp.WtB = WtqB; wp.Wt2 = Wtq2;
    wp.bqe1 = bqe1; wp.bqe2 = bqe2;
    hipLaunchKernelGGL(make_wqe, dim3(194), dim3(256), 0, stream, wp, flags);

    (void)hipMemsetAsync(deg, 0, (size_t)N * 4, stream);
    hipLaunchKernelGGL(count_deg, dim3((E + 255) / 256), dim3(256), 0, stream, ei, flags, deg, E);
    hipLaunchKernelGGL(scan_a, dim3(NB196), dim3(256), 0, stream, deg, bsum, N);
    hipLaunchKernelGGL(scan_b, dim3(1), dim3(256), 0, stream, bsum, NB196);
    hipLaunchKernelGGL(scan_c, dim3(NB196), dim3(256), 0, stream, deg, bsum, row_ptr, cursor, N);
    hipLaunchKernelGGL(fill_csr, dim3((E + 255) / 256), dim3(256), 0, stream, ei, flags, cursor,
                       srcs, eids, E);

    hipLaunchKernelGGL(gather_ef, dim3(E * 4 / 256), dim3(256), 0, stream,
                       eids, ef, flags, efg, E);

    const int gN = (N + 63) / 64;   // 782
    const int gA = (N + 3) / 4;     // 12500

    // layer 1: q,k,v,sk + qWe (two halves)
    {
        GemmSets S;
        S.Wt[0] = WtQ1; S.bias[0] = bq1;  S.O[0] = q;    S.bf32[0] = 0;
        S.Wt[1] = WtK1; S.bias[1] = bk1;  S.O[1] = k;    S.bf32[1] = 0;
        S.Wt[2] = WtV1; S.bias[2] = bv1;  S.O[2] = v;    S.bf32[2] = 0;
        S.Wt[3] = WtS1; S.bias[3] = bs1;  S.O[3] = sk;   S.bf32[3] = 0;
        S.Wt[4] = WtqA; S.bias[4] = bqe1;       S.O[4] = qweA; S.bf32[4] = 1;
        S.Wt[5] = WtqB; S.bias[5] = bqe1 + 128; S.O[5] = qweB; S.bf32[5] = 1;
        hipLaunchKernelGGL(gemm128, dim3(gN, 6), dim3(256), 0, stream, xbf, flags, S, N);
    }
    hipLaunchKernelGGL((attn_kernel<8, 0>), dim3(gA), dim3(256), 0, stream,
                       row_ptr, srcs, q, k, v, efg, qweA, qweB, sk, We1, flags, (void*)h, N);

    // layer 2: q,k,v,sk + qWe2
    {
        GemmSets S;
        S.Wt[0] = WtQ2; S.bias[0] = bq2;  S.O[0] = q;    S.bf32[0] = 0;
        S.Wt[1] = WtK2; S.bias[1] = bk2;  S.O[1] = k;    S.bf32[1] = 0;
        S.Wt[2] = WtV2; S.bias[2] = bv2;  S.O[2] = v;    S.bf32[2] = 0;
        S.Wt[3] = WtS2; S.bias[3] = bs2;  S.O[3] = sk;   S.bf32[3] = 0;
        S.Wt[4] = Wtq2; S.bias[4] = bqe2; S.O[4] = qwe2; S.bf32[4] = 1;
        S.Wt[5] = Wtq2; S.bias[5] = bqe2; S.O[5] = qwe2; S.bf32[5] = 1;
        hipLaunchKernelGGL(gemm128, dim3(gN, 5), dim3(256), 0, stream, h, flags, S, N);
    }
    hipLaunchKernelGGL((attn_kernel<1, 1>), dim3(gA), dim3(256), 0, stream,
                       row_ptr, srcs, q, k, v, efg, qwe2, qwe2, sk, We2, flags, d_out, N);
}

// Round 2
// 517.923 us; speedup vs baseline: 1.0554x; 1.0554x over previous
//
#include <hip/hip_runtime.h>

// GraphAttentionEmbedding: 2x TransformerConv (PyG) on MI355X (gfx950).
// N=50000, E=400000, IN=128, H1=8*16=128, OUT=128, EDIM=32.
// PROVEN: fp32 inputs (runtime-detected), fp32 output; internal bf16+fp32 acc.
// R15 (ee-factorization) regressed attn 56.7->113us: F@We LDS epilogue ~= whole
// edge-loop cost at avg degree 8; We-LDS staging + barrier dropped occupancy.
// R16: keep factorization, repair attn:
//   - zero LDS: We cols in 32 VGPRs loaded AFTER edge loop; F broadcast via
//     ds_swizzle (lane&0x18)|src within 8-lane head group (1 inst).
//   - masked batch-8 edge loop (degrees ~Poisson(8): old scalar tail was ~44%
//     of edges with no load batching).
//   - k/v packed in one kv[node][256] row (gemm pitch) -> 1 gather row/edge.

using u16 = unsigned short;
using u32 = unsigned int;

#define NODES 50000
#define EDGES 400000
#define NB196 196   // ceil(50000/256)

typedef __attribute__((ext_vector_type(8))) short bf16x8;
typedef __attribute__((ext_vector_type(4))) float f32x4;

__device__ __forceinline__ float bflo(u32 u) { return __uint_as_float(u << 16); }
__device__ __forceinline__ float bfhi(u32 u) { return __uint_as_float(u & 0xffff0000u); }
__device__ __forceinline__ u16 f2bf(float f) {
    u32 u = __float_as_uint(f);
    u += 0x7fffu + ((u >> 16) & 1u);   // RNE
    return (u16)(u >> 16);
}
__device__ __forceinline__ u32 pack2(float a, float b) {
    return (u32)f2bf(a) | ((u32)f2bf(b) << 16);
}
__device__ __forceinline__ float rdv(const void* p, int i, int f) {
    return f ? ((const float*)p)[i]
             : __uint_as_float(((u32) reinterpret_cast<const u16*>(p)[i]) << 16);
}

// DPP lane-add at VALU speed (no DS pipe).
template <int CTRL>
__device__ __forceinline__ float dpp_addf(float x) {
    int y = __builtin_amdgcn_update_dpp(0, __float_as_int(x), CTRL, 0xF, 0xF, true);
    return x + __int_as_float(y);
}
template <int GRP>
__device__ __forceinline__ float grp_sum(float p, int lane) {
    p = dpp_addf<0xB1>(p);    // xor 1
    p = dpp_addf<0x4E>(p);    // xor 2
    p = dpp_addf<0x141>(p);   // xor 4 (8-group done)
    if (GRP == 64) {
        p = dpp_addf<0x140>(p);   // xor 8
        p += __int_as_float(__builtin_amdgcn_ds_swizzle(__float_as_int(p), 0x401F)); // xor16
        p += __int_as_float(__builtin_amdgcn_ds_bpermute((lane ^ 32) << 2,
                                                         __float_as_int(p)));        // xor32
    }
    return p;
}

// Broadcast lane ((lane&0x18)|SRC)'s value to its 8-lane group (BitMode swizzle).
template <int SRC>
__device__ __forceinline__ float bcast8(float x) {
    return __int_as_float(__builtin_amdgcn_ds_swizzle(__float_as_int(x),
                                                      0x18 | (SRC << 5)));
}

// ---------------- diagnostic sentinel (fp32 out) ----------------------------
__global__ __launch_bounds__(256) void fill_sentinel(float* __restrict__ out, int n, float val) {
    int i = blockIdx.x * 256 + threadIdx.x;
    if (i < n) out[i] = val;
}

// ---------------- runtime format detection (one wave) -----------------------
__global__ __launch_bounds__(64) void detect_fmt(const u32* __restrict__ xw,
                                                 const int* __restrict__ eraw,
                                                 int* __restrict__ flags) {
    int lane = threadIdx.x;
    u32 e = (xw[lane] >> 7) & 0xffu;
    unsigned long long sane = __ballot(e >= 90u && e <= 141u);
    unsigned long long zodd = __ballot(eraw[1 + 2 * lane] == 0);
    if (lane == 0) {
        flags[0] = (sane == ~0ull) ? 0 : 1;   // 1 = fp32
        flags[1] = (zodd == ~0ull) ? 1 : 0;   // 1 = int64
    }
}

// ---------------- x -> bf16 conversion (once) -------------------------------
__global__ __launch_bounds__(256) void convert_x(const void* __restrict__ X,
                                                 const int* __restrict__ flags,
                                                 u16* __restrict__ xbf, int total) {
    int i = (blockIdx.x * 256 + threadIdx.x) * 8;
    if (i >= total) return;
    if (flags[0]) {
        const float* xf = (const float*)X + i;
        float4 lo = *reinterpret_cast<const float4*>(xf);
        float4 hi = *reinterpret_cast<const float4*>(xf + 4);
        uint4 val = make_uint4(pack2(lo.x, lo.y), pack2(lo.z, lo.w),
                               pack2(hi.x, hi.y), pack2(hi.z, hi.w));
        *reinterpret_cast<uint4*>(xbf + i) = val;
    } else {
        *reinterpret_cast<uint4*>(xbf + i) =
            *reinterpret_cast<const uint4*>((const u16*)X + i);
    }
}

// ---------------- weight transpose+convert: W[K][128] -> Wt[128][K] bf16 ----
struct TPtrs {
    const void* src[8];
    u16*        dst[8];
    int         K[8];
};

__global__ __launch_bounds__(256) void transpose_w(TPtrs P, const int* __restrict__ fmt) {
    int m = blockIdx.x;
    int f = *fmt;
    int K = P.K[m];
    int quarter = (K * 128) >> 2;
    u16* d = P.dst[m];
    int base = blockIdx.y * quarter;
    const float* sf = (const float*)P.src[m];
    const u16*   sb = (const u16*)P.src[m];
    for (int idx = base + threadIdx.x; idx < base + quarter; idx += 256) {
        int k = idx >> 7, n = idx & 127;
        d[n * K + k] = f ? f2bf(sf[idx]) : sb[idx];
    }
}

// ---------------- combined weights: Wqe = Wq (.) We per head ----------------
// L1: Wqe1[i, h*32+d] = sum_{c<16} Wq1[i,16h+c]*We1[d,16h+c]  (h=0..7)
//     -> Wt format split: WtA (cols 0..127 = h<4), WtB (h>=4).
// L2: Wqe2[i, d] = sum_{c<128} Wq2[i,c]*We2[d,c]  (d=0..31; cols 32..127 = 0)
// biases: bqe1[256], bqe2[128] (fp32).
struct WqeP {
    const void *Wq1, *We1, *bq1, *Wq2, *We2, *bq2;
    u16 *WtA, *WtB, *Wt2;
    float *bqe1, *bqe2;
};

__global__ __launch_bounds__(256) void make_wqe(WqeP P, const int* __restrict__ flags) {
    int f = flags[0];
    int idx = blockIdx.x * 256 + threadIdx.x;
    if (idx < 32768) {                          // layer-1 weights
        int col = idx >> 7, i = idx & 127;
        int hh = col >> 5, d = col & 31;
        float s = 0.f;
#pragma unroll
        for (int c = 0; c < 16; ++c)
            s += rdv(P.Wq1, i * 128 + hh * 16 + c, f) * rdv(P.We1, d * 128 + hh * 16 + c, f);
        if (col < 128) P.WtA[col * 128 + i] = f2bf(s);
        else           P.WtB[(col - 128) * 128 + i] = f2bf(s);
    } else if (idx < 49152) {                   // layer-2 weights (zero-padded)
        int t = idx - 32768;
        int col = t >> 7, i = t & 127;
        float s = 0.f;
        if (col < 32) {
            for (int c = 0; c < 128; ++c)
                s += rdv(P.Wq2, i * 128 + c, f) * rdv(P.We2, col * 128 + c, f);
        }
        P.Wt2[col * 128 + i] = f2bf(s);
    } else if (idx < 49408) {                   // bqe1
        int col = idx - 49152;
        int hh = col >> 5, d = col & 31;
        float s = 0.f;
#pragma unroll
        for (int c = 0; c < 16; ++c)
            s += rdv(P.bq1, hh * 16 + c, f) * rdv(P.We1, d * 128 + hh * 16 + c, f);
        P.bqe1[col] = s;
    } else if (idx < 49536) {                   // bqe2
        int d = idx - 49408;
        float s = 0.f;
        if (d < 32)
            for (int c = 0; c < 128; ++c)
                s += rdv(P.bq2, c, f) * rdv(P.We2, d * 128 + c, f);
        P.bqe2[d] = s;
    }
}

// ---------------- CSR build (by dst) ----------------------------------------
__global__ __launch_bounds__(256) void count_deg(const int* __restrict__ raw,
                                                 const int* __restrict__ flags,
                                                 int* __restrict__ deg, int E) {
    int e = blockIdx.x * 256 + threadIdx.x;
    if (e < E) {
        int f = flags[1];
        int d = f ? raw[2 * (E + e)] : raw[E + e];
        if ((unsigned)d < (unsigned)NODES) atomicAdd(&deg[d], 1);
    }
}

__device__ __forceinline__ int block_scan256(int v) {
    __shared__ int ws[4];
    int t = threadIdx.x, lane = t & 63, w = t >> 6;
    int x = v;
#pragma unroll
    for (int off = 1; off < 64; off <<= 1) {
        int y = __shfl_up(x, off, 64);
        if (lane >= off) x += y;
    }
    if (lane == 63) ws[w] = x;
    __syncthreads();
#pragma unroll
    for (int j = 0; j < 3; ++j)
        if (j < w) x += ws[j];
    return x;
}

__global__ __launch_bounds__(256) void scan_a(const int* __restrict__ deg,
                                              int* __restrict__ bsum, int n) {
    int i = blockIdx.x * 256 + threadIdx.x;
    int v = (i < n) ? deg[i] : 0;
    int incl = block_scan256(v);
    if (threadIdx.x == 255) bsum[blockIdx.x] = incl;
}

__global__ __launch_bounds__(256) void scan_b(int* __restrict__ bsum, int nb) {
    int t = threadIdx.x;
    int v = (t < nb) ? bsum[t] : 0;
    int incl = block_scan256(v);
    if (t < nb) bsum[t] = incl - v;
}

__global__ __launch_bounds__(256) void scan_c(const int* __restrict__ deg,
                                              const int* __restrict__ bsum,
                                              int* __restrict__ row_ptr,
                                              int* __restrict__ cursor, int n) {
    int b = blockIdx.x;
    int i = b * 256 + threadIdx.x;
    int v = (i < n) ? deg[i] : 0;
    int incl = block_scan256(v) + bsum[b];
    if (i < n) {
        row_ptr[i + 1] = incl;
        cursor[i] = incl - v;
    }
    if (i == 0) row_ptr[0] = 0;
}

__global__ __launch_bounds__(256) void fill_csr(const int* __restrict__ raw,
                                                const int* __restrict__ flags,
                                                int* __restrict__ cursor,
                                                int* __restrict__ srcs,
                                                int* __restrict__ eids, int E) {
    int e = blockIdx.x * 256 + threadIdx.x;
    if (e < E) {
        int f = flags[1];
        int d = f ? raw[2 * (E + e)] : raw[E + e];
        int s = f ? raw[2 * e] : raw[e];
        if ((unsigned)d < (unsigned)NODES && (unsigned)s < (unsigned)NODES) {
            int pos = atomicAdd(&cursor[d], 1);
            if ((unsigned)pos < (unsigned)E) { srcs[pos] = s; eids[pos] = e; }
        }
    }
}

// ---------------- ef gather to CSR order, bf16 (shared by both layers) ------
__global__ __launch_bounds__(256) void gather_ef(const int* __restrict__ eids,
                                                 const void* __restrict__ EF,
                                                 const int* __restrict__ flags,
                                                 u16* __restrict__ EFG, int E) {
    int t = blockIdx.x * 256 + threadIdx.x;
    int pos = t >> 2, seg = t & 3;
    if (pos >= E) return;
    int e = eids[pos];
    uint4 val;
    if (flags[0]) {
        const float* src = (const float*)EF + (size_t)e * 32 + seg * 8;
        float4 lo = *reinterpret_cast<const float4*>(src);
        float4 hi = *reinterpret_cast<const float4*>(src + 4);
        val = make_uint4(pack2(lo.x, lo.y), pack2(lo.z, lo.w),
                         pack2(hi.x, hi.y), pack2(hi.z, hi.w));
    } else {
        val = *reinterpret_cast<const uint4*>((const u16*)EF + (size_t)e * 32 + seg * 8);
    }
    *reinterpret_cast<uint4*>(EFG + (size_t)pos * 32 + seg * 8) = val;
}

// ---------------- GEMM: O[M,128] = A[M,128] @ Wt[128,128]^T + bias ----------
// LDS-staged A (bf16, pre-converted) + B; one weight set per block (grid.y).
// Operand-swapped MFMA: lane acc[nt] = 4 consecutive out-cols of one row
// -> epilogue is 8 coalesced uint2 stores (verified R13/R14).
struct GemmSets {
    const u16*  Wt[6];
    const void* bias[6];
    u16*        O[6];
    int         bf32[6];    // 1 = bias is fp32 always, 0 = follow input flags
    int         pitch[6];   // output row pitch in u16 elements
};

__global__ __launch_bounds__(256) void gemm128(
    const u16* __restrict__ A, const int* __restrict__ flags, GemmSets S, int M) {
    constexpr int K = 128;
    constexpr int PAD = K + 8;
    constexpr int KV = K / 8;
    __shared__ u16 Asl[64 * PAD];
    __shared__ u16 Bsl[128 * PAD];

    const u16*  Wt   = S.Wt[blockIdx.y];
    const void* bias = S.bias[blockIdx.y];
    u16*        O    = S.O[blockIdx.y];
    int pitch = S.pitch[blockIdx.y];
    int f = S.bf32[blockIdx.y] ? 1 : flags[0];
    int m0 = blockIdx.x * 64;

    for (int idx = threadIdx.x; idx < 64 * KV; idx += 256) {
        int r = idx / KV, cv = idx % KV;
        int gr = m0 + r;
        uint4 val = make_uint4(0, 0, 0, 0);
        if (gr < M) val = *reinterpret_cast<const uint4*>(A + (size_t)gr * K + cv * 8);
        *reinterpret_cast<uint4*>(&Asl[r * PAD + cv * 8]) = val;
    }
    for (int idx = threadIdx.x; idx < 128 * KV; idx += 256) {
        int r = idx / KV, cv = idx % KV;
        *reinterpret_cast<uint4*>(&Bsl[r * PAD + cv * 8]) =
            *reinterpret_cast<const uint4*>(Wt + r * K + cv * 8);
    }
    __syncthreads();

    int lane = threadIdx.x & 63, wv = threadIdx.x >> 6;
    int l15 = lane & 15;
    int quad = lane >> 4;
    int kq = quad * 8;

    f32x4 b4[8];
#pragma unroll
    for (int nt = 0; nt < 8; ++nt) {
        int col0 = nt * 16 + quad * 4;
        if (bias) {
            if (f) {
                b4[nt] = *reinterpret_cast<const f32x4*>((const float*)bias + col0);
            } else {
                uint2 bu = *reinterpret_cast<const uint2*>((const u16*)bias + col0);
                b4[nt][0] = bflo(bu.x); b4[nt][1] = bfhi(bu.x);
                b4[nt][2] = bflo(bu.y); b4[nt][3] = bfhi(bu.y);
            }
        } else {
            b4[nt][0] = b4[nt][1] = b4[nt][2] = b4[nt][3] = 0.f;
        }
    }

    f32x4 acc[8] = {};
#pragma unroll
    for (int k0 = 0; k0 < K; k0 += 32) {
        bf16x8 xf = *reinterpret_cast<const bf16x8*>(&Asl[(wv * 16 + l15) * PAD + k0 + kq]);
#pragma unroll
        for (int nt = 0; nt < 8; ++nt) {
            bf16x8 wf = *reinterpret_cast<const bf16x8*>(&Bsl[(nt * 16 + l15) * PAD + k0 + kq]);
            acc[nt] = __builtin_amdgcn_mfma_f32_16x16x32_bf16(wf, xf, acc[nt], 0, 0, 0);
        }
    }

    int row = m0 + wv * 16 + l15;
    if (row < M) {
        u16* Orow = O + (size_t)row * pitch;
#pragma unroll
        for (int nt = 0; nt < 8; ++nt) {
            uint2 pk;
            pk.x = pack2(acc[nt][0] + b4[nt][0], acc[nt][1] + b4[nt][1]);
            pk.y = pack2(acc[nt][2] + b4[nt][2], acc[nt][3] + b4[nt][3]);
            *reinterpret_cast<uint2*>(Orow + nt * 16 + quad * 4) = pk;
        }
    }
}

// ---------------- attention: factorized ee, zero-LDS, masked batch-8 --------
// Per wave = one dst node; lane (h=lane>>3, j=lane&7) owns channels 16h+2j..+1
// and ef dims 4j..4j+3. Score: p = q.k + qw.ef (group-summed). Value: a += w*v,
// f[0..3] += w*ef; epilogue broadcasts F via ds_swizzle and applies We from
// 32 VGPRs (loaded after the edge loop; We is L2-resident, 16KB).
template <int HEADS, int F32OUT>
__global__ __launch_bounds__(256) void attn_kernel(
    const int* __restrict__ row_ptr, const int* __restrict__ srcs,
    const u16* __restrict__ Q, const u16* __restrict__ KV,
    const u16* __restrict__ EFG,
    const u16* __restrict__ QWA, const u16* __restrict__ QWB,
    const u16* __restrict__ SK, const void* __restrict__ We,
    const int* __restrict__ flags, void* __restrict__ OUT, int nn) {
    int wv = threadIdx.x >> 6, lane = threadIdx.x & 63;
    int node = blockIdx.x * 4 + wv;
    if (node >= nn) return;
    int h = lane >> 3, j = lane & 7;
    int c0 = lane * 2;

    const float scale = (HEADS == 8) ? 0.25f : 0.08838834764831845f;  // 1/sqrt(C)
    const float escale = (HEADS == 8) ? scale : scale * 0.125f;       // /8 replicas
    constexpr int GRP = (HEADS == 8) ? 8 : 64;

    u32 qb = *reinterpret_cast<const u32*>(Q + (size_t)node * 128 + c0);
    float q0 = bflo(qb) * scale, q1 = bfhi(qb) * scale;

    const u16* qp = (HEADS == 8)
        ? ((h < 4 ? QWA : QWB) + (size_t)node * 128 + (h & 3) * 32 + j * 4)
        : (QWA + (size_t)node * 128 + j * 4);
    uint2 qwu = *reinterpret_cast<const uint2*>(qp);
    float qw0 = bflo(qwu.x) * escale, qw1 = bfhi(qwu.x) * escale;
    float qw2 = bflo(qwu.y) * escale, qw3 = bfhi(qwu.y) * escale;

    int beg = row_ptr[node], end = row_ptr[node + 1];
    float l_run = 0.f, a0 = 0.f, a1 = 0.f;
    float f0 = 0.f, f1 = 0.f, f2 = 0.f, f3 = 0.f;

    const u16* efp = EFG + j * 4;

    auto edge_step = [&](u32 kbv, u32 vbv, uint2 ebv, bool valid) {
        float e0 = bflo(ebv.x), e1 = bfhi(ebv.x);
        float e2 = bflo(ebv.y), e3 = bfhi(ebv.y);
        float pa = q0 * bflo(kbv);
        pa = fmaf(q1, bfhi(kbv), pa);
        float pb = qw0 * e0;
        pb = fmaf(qw1, e1, pb);
        pa = fmaf(qw2, e2, pa);
        pb = fmaf(qw3, e3, pb);
        float p = grp_sum<GRP>(pa + pb, lane);
        float w = __expf(p);
        w = valid ? w : 0.f;
        l_run += w;
        a0 = fmaf(w, bflo(vbv), a0);
        a1 = fmaf(w, bfhi(vbv), a1);
        f0 = fmaf(w, e0, f0); f1 = fmaf(w, e1, f1);
        f2 = fmaf(w, e2, f2); f3 = fmaf(w, e3, f3);
    };

    // all edges through masked full-width batches (degrees ~Poisson(8))
    for (int i = beg; i < end; i += 8) {
        int kleft = end - i;
        int pcl[8], sA[8];
#pragma unroll
        for (int t = 0; t < 8; ++t) {
            int idx = i + t;
            pcl[t] = (idx < end) ? idx : (end - 1);
            sA[t] = srcs[pcl[t]];
        }
        u32 kb[8], vb[8]; uint2 eb[8];
#pragma unroll
        for (int t = 0; t < 8; ++t) {
            const u16* kp = KV + (size_t)sA[t] * 256 + c0;
            kb[t] = *reinterpret_cast<const u32*>(kp);
            vb[t] = *reinterpret_cast<const u32*>(kp + 128);
            eb[t] = *reinterpret_cast<const uint2*>(efp + (size_t)pcl[t] * 32);
        }
#pragma unroll
        for (int t = 0; t < 8; ++t) edge_step(kb[t], vb[t], eb[t], t < kleft);
    }

    // ---- We columns for this lane (loaded late: short live range) ----------
    int fmt = flags[0];
    u32 weReg[32];
    if (fmt) {
        const float* Wf = (const float*)We;
#pragma unroll
        for (int d = 0; d < 32; ++d) {
            float2 w2 = *reinterpret_cast<const float2*>(Wf + d * 128 + c0);
            weReg[d] = pack2(w2.x, w2.y);
        }
    } else {
        const u16* Wb = (const u16*)We;
#pragma unroll
        for (int d = 0; d < 32; ++d)
            weReg[d] = *reinterpret_cast<const u32*>(Wb + d * 128 + c0);
    }

    // ---- epilogue: out_ee[c] = sum_d F[d] * We[d][c], F via swizzle bcast --
    float acc0 = 0.f, acc1 = 0.f;
#define EPI(SRC) do { \
        float F0 = bcast8<SRC>(f0), F1 = bcast8<SRC>(f1); \
        float F2 = bcast8<SRC>(f2), F3 = bcast8<SRC>(f3); \
        u32 w0 = weReg[4*SRC], w1 = weReg[4*SRC+1]; \
        u32 w2 = weReg[4*SRC+2], w3 = weReg[4*SRC+3]; \
        acc0 = fmaf(F0, bflo(w0), acc0); acc1 = fmaf(F0, bfhi(w0), acc1); \
        acc0 = fmaf(F1, bflo(w1), acc0); acc1 = fmaf(F1, bfhi(w1), acc1); \
        acc0 = fmaf(F2, bflo(w2), acc0); acc1 = fmaf(F2, bfhi(w2), acc1); \
        acc0 = fmaf(F3, bflo(w3), acc0); acc1 = fmaf(F3, bfhi(w3), acc1); \
    } while (0)
    EPI(0); EPI(1); EPI(2); EPI(3); EPI(4); EPI(5); EPI(6); EPI(7);
#undef EPI

    float inv = 1.f / fmaxf(l_run, 1e-16f);
    u32 sb = *reinterpret_cast<const u32*>(SK + (size_t)node * 128 + c0);
    float o0 = fmaxf(fmaf(a0 + acc0, inv, bflo(sb)), 0.f);
    float o1 = fmaxf(fmaf(a1 + acc1, inv, bfhi(sb)), 0.f);
    if (F32OUT) {
        *reinterpret_cast<float2*>((float*)OUT + (size_t)node * 128 + c0) = make_float2(o0, o1);
    } else {
        *reinterpret_cast<u32*>((u16*)OUT + (size_t)node * 128 + c0) = pack2(o0, o1);
    }
}

// ---------------------------------------------------------------------------
extern "C" void kernel_launch(void* const* d_in, const int* in_sizes, int n_in,
                              void* d_out, int out_size, void* d_ws, size_t ws_size,
                              hipStream_t stream) {
    const int N = NODES, E = EDGES;
    const void* x  = d_in[0];
    const int*  ei = (const int*)d_in[1];
    const void* ef = d_in[2];
    const void* Wq1 = d_in[3];  const void* bq1 = d_in[4];
    const void* Wk1 = d_in[5];  const void* bk1 = d_in[6];
    const void* Wv1 = d_in[7];  const void* bv1 = d_in[8];
    const void* We1 = d_in[9];
    const void* Ws1 = d_in[10]; const void* bs1 = d_in[11];
    const void* Wq2 = d_in[12]; const void* bq2 = d_in[13];
    const void* Wk2 = d_in[14]; const void* bk2 = d_in[15];
    const void* Wv2 = d_in[16]; const void* bv2 = d_in[17];
    const void* We2 = d_in[18];
    const void* Ws2 = d_in[19]; const void* bs2 = d_in[20];

    char* ws = (char*)d_ws;
    size_t off = 0;
    auto carve = [&](size_t bytes) -> void* {
        void* p = ws + off;
        off += (bytes + 255) & ~(size_t)255;
        return p;
    };

    u16* WtQ1 = (u16*)carve(128 * 128 * 2);
    u16* WtK1 = (u16*)carve(128 * 128 * 2);
    u16* WtV1 = (u16*)carve(128 * 128 * 2);
    u16* WtS1 = (u16*)carve(128 * 128 * 2);
    u16* WtQ2 = (u16*)carve(128 * 128 * 2);
    u16* WtK2 = (u16*)carve(128 * 128 * 2);
    u16* WtV2 = (u16*)carve(128 * 128 * 2);
    u16* WtS2 = (u16*)carve(128 * 128 * 2);
    u16* WtqA = (u16*)carve(128 * 128 * 2);
    u16* WtqB = (u16*)carve(128 * 128 * 2);
    u16* Wtq2 = (u16*)carve(128 * 128 * 2);
    float* bqe1 = (float*)carve(256 * 4);
    float* bqe2 = (float*)carve(128 * 4);
    int* flags   = (int*)carve(256);
    int* deg     = (int*)carve((size_t)N * 4);
    int* bsum    = (int*)carve((size_t)NB196 * 4);
    int* row_ptr = (int*)carve((size_t)(N + 1) * 4);
    int* cursor  = (int*)carve((size_t)N * 4);
    int* srcs    = (int*)carve((size_t)E * 4);
    int* eids    = (int*)carve((size_t)E * 4);
    u16* xbf  = (u16*)carve((size_t)N * 128 * 2);
    u16* q    = (u16*)carve((size_t)N * 128 * 2);
    u16* kv   = (u16*)carve((size_t)N * 256 * 2);   // k rows [0:128], v rows [128:256]
    u16* sk   = (u16*)carve((size_t)N * 128 * 2);
    u16* h    = (u16*)carve((size_t)N * 128 * 2);
    u16* qweA = (u16*)carve((size_t)N * 128 * 2);
    u16* qweB = (u16*)carve((size_t)N * 128 * 2);
    u16* qwe2 = (u16*)carve((size_t)N * 128 * 2);
    u16* efg  = (u16*)carve((size_t)E * 32 * 2);
    const size_t REQ = off;   // ~146 MB

    if (ws_size < REQ) {
        hipLaunchKernelGGL(fill_sentinel, dim3((out_size + 255) / 256), dim3(256), 0, stream,
                           (float*)d_out, out_size, 16.0f * (float)(ws_size >> 20));
        return;
    }

    hipLaunchKernelGGL(detect_fmt, dim3(1), dim3(64), 0, stream, (const u32*)x, ei, flags);

    hipLaunchKernelGGL(convert_x, dim3((N * 128 / 8 + 255) / 256), dim3(256), 0, stream,
                       x, flags, xbf, N * 128);

    TPtrs tp;
    tp.src[0] = Wq1; tp.dst[0] = WtQ1; tp.K[0] = 128;
    tp.src[1] = Wk1; tp.dst[1] = WtK1; tp.K[1] = 128;
    tp.src[2] = Wv1; tp.dst[2] = WtV1; tp.K[2] = 128;
    tp.src[3] = Ws1; tp.dst[3] = WtS1; tp.K[3] = 128;
    tp.src[4] = Wq2; tp.dst[4] = WtQ2; tp.K[4] = 128;
    tp.src[5] = Wk2; tp.dst[5] = WtK2; tp.K[5] = 128;
    tp.src[6] = Wv2; tp.dst[6] = WtV2; tp.K[6] = 128;
    tp.src[7] = Ws2; tp.dst[7] = WtS2; tp.K[7] = 128;
    hipLaunchKernelGGL(transpose_w, dim3(8, 4), dim3(256), 0, stream, tp, flags);

    WqeP wp;
    wp.Wq1 = Wq1; wp.We1 = We1; wp.bq1 = bq1;
    wp.Wq2 = Wq2; wp.We2 = We2; wp.bq2 = bq2;
    wp.WtA = WtqA; wp.WtB = WtqB; wp.Wt2 = Wtq2;
    wp.bqe1 = bqe1; wp.bqe2 = bqe2;
    hipLaunchKernelGGL(make_wqe, dim3(194), dim3(256), 0, stream, wp, flags);

    (void)hipMemsetAsync(deg, 0, (size_t)N * 4, stream);
    hipLaunchKernelGGL(count_deg, dim3((E + 255) / 256), dim3(256), 0, stream, ei, flags, deg, E);
    hipLaunchKernelGGL(scan_a, dim3(NB196), dim3(256), 0, stream, deg, bsum, N);
    hipLaunchKernelGGL(scan_b, dim3(1), dim3(256), 0, stream, bsum, NB196);
    hipLaunchKernelGGL(scan_c, dim3(NB196), dim3(256), 0, stream, deg, bsum, row_ptr, cursor, N);
    hipLaunchKernelGGL(fill_csr, dim3((E + 255) / 256), dim3(256), 0, stream, ei, flags, cursor,
                       srcs, eids, E);

    hipLaunchKernelGGL(gather_ef, dim3(E * 4 / 256), dim3(256), 0, stream,
                       eids, ef, flags, efg, E);

    const int gN = (N + 63) / 64;   // 782
    const int gA = (N + 3) / 4;     // 12500

    // layer 1: q,k,v,sk + qWe (two halves)
    {
        GemmSets S;
        S.Wt[0] = WtQ1; S.bias[0] = bq1;  S.O[0] = q;        S.bf32[0] = 0; S.pitch[0] = 128;
        S.Wt[1] = WtK1; S.bias[1] = bk1;  S.O[1] = kv;       S.bf32[1] = 0; S.pitch[1] = 256;
        S.Wt[2] = WtV1; S.bias[2] = bv1;  S.O[2] = kv + 128; S.bf32[2] = 0; S.pitch[2] = 256;
        S.Wt[3] = WtS1; S.bias[3] = bs1;  S.O[3] = sk;       S.bf32[3] = 0; S.pitch[3] = 128;
        S.Wt[4] = WtqA; S.bias[4] = bqe1;       S.O[4] = qweA; S.bf32[4] = 1; S.pitch[4] = 128;
        S.Wt[5] = WtqB; S.bias[5] = bqe1 + 128; S.O[5] = qweB; S.bf32[5] = 1; S.pitch[5] = 128;
        hipLaunchKernelGGL(gemm128, dim3(gN, 6), dim3(256), 0, stream, xbf, flags, S, N);
    }
    hipLaunchKernelGGL((attn_kernel<8, 0>), dim3(gA), dim3(256), 0, stream,
                       row_ptr, srcs, q, kv, efg, qweA, qweB, sk, We1, flags, (void*)h, N);

    // layer 2: q,k,v,sk + qWe2
    {
        GemmSets S;
        S.Wt[0] = WtQ2; S.bias[0] = bq2;  S.O[0] = q;        S.bf32[0] = 0; S.pitch[0] = 128;
        S.Wt[1] = WtK2; S.bias[1] = bk2;  S.O[1] = kv;       S.bf32[1] = 0; S.pitch[1] = 256;
        S.Wt[2] = WtV2; S.bias[2] = bv2;  S.O[2] = kv + 128; S.bf32[2] = 0; S.pitch[2] = 256;
        S.Wt[3] = WtS2; S.bias[3] = bs2;  S.O[3] = sk;       S.bf32[3] = 0; S.pitch[3] = 128;
        S.Wt[4] = Wtq2; S.bias[4] = bqe2; S.O[4] = qwe2;     S.bf32[4] = 1; S.pitch[4] = 128;
        S.Wt[5] = Wtq2; S.bias[5] = bqe2; S.O[5] = qwe2;     S.bf32[5] = 1; S.pitch[5] = 128;
        hipLaunchKernelGGL(gemm128, dim3(gN, 5), dim3(256), 0, stream, h, flags, S, N);
    }
    hipLaunchKernelGGL((attn_kernel<1, 1>), dim3(gA), dim3(256), 0, stream,
                       row_ptr, srcs, q, kv, efg, qwe2, qwe2, sk, We2, flags, d_out, N);
}

// Round 3
// 442.700 us; speedup vs baseline: 1.2348x; 1.1699x over previous
//
#include <hip/hip_runtime.h>

// GraphAttentionEmbedding: 2x TransformerConv (PyG) on MI355X (gfx950).
// N=50000, E=400000, IN=128, H1=8*16=128, OUT=128, EDIM=32.
// PROVEN: fp32 inputs (runtime-detected), fp32 output; internal bf16+fp32 acc.
// R15/R16 lesson: factorized ee (score via qWe.ef, value via F@We) removes
// 36MB fetch + gemm_ee, but naive impl is VALU-bound: 45 ops/edge x1.41 pad
// waste + 160-op/node epilogue = 3x R14's VALU cycles (104us vs 56.7us attn).
// R17: same algorithm, VALU-lean attn:
//   - readfirstlane(beg/end) -> scalar edge addressing (s_load srcs, SGPR kv/ef
//     bases); lanes only add loop-invariant c0.
//   - v_dot2_f32_bf16 (guarded, fma fallback) for score + epilogue; scale
//     applied post-sum as exp2(p*s2); L2's /8 replication baked into Wtq2/bqe2.
//   - exact-8 main loop + masked-4 tail (pad waste 1.41x -> 1.11x).
//   - We pre-packed along d (WeP) -> 56-op/node epilogue; 4 nodes per wave
//     amortize WeP loads and average wave-exit imbalance.

using u16 = unsigned short;
using u32 = unsigned int;

#define NODES 50000
#define EDGES 400000
#define NB196 196   // ceil(50000/256)

typedef __attribute__((ext_vector_type(8))) short bf16x8;
typedef __attribute__((ext_vector_type(4))) float f32x4;

__device__ __forceinline__ float bflo(u32 u) { return __uint_as_float(u << 16); }
__device__ __forceinline__ float bfhi(u32 u) { return __uint_as_float(u & 0xffff0000u); }
__device__ __forceinline__ u16 f2bf(float f) {
    u32 u = __float_as_uint(f);
    u += 0x7fffu + ((u >> 16) & 1u);   // RNE
    return (u16)(u >> 16);
}
__device__ __forceinline__ u32 pack2(float a, float b) {
    return (u32)f2bf(a) | ((u32)f2bf(b) << 16);
}
__device__ __forceinline__ float rdv(const void* p, int i, int f) {
    return f ? ((const float*)p)[i]
             : __uint_as_float(((u32) reinterpret_cast<const u16*>(p)[i]) << 16);
}

// dot2 on packed bf16 pairs: p = a.lo*b.lo + a.hi*b.hi + c
#if __has_builtin(__builtin_amdgcn_fdot2_f32_bf16)
typedef __attribute__((ext_vector_type(2))) __bf16 bf2;
__device__ __forceinline__ float dot2bf(u32 a, u32 b, float c) {
    return __builtin_amdgcn_fdot2_f32_bf16(__builtin_bit_cast(bf2, a),
                                           __builtin_bit_cast(bf2, b), c, false);
}
#else
__device__ __forceinline__ float dot2bf(u32 a, u32 b, float c) {
    return fmaf(bflo(a), bflo(b), fmaf(bfhi(a), bfhi(b), c));
}
#endif

__device__ __forceinline__ float fexp2(float x) {
#if __has_builtin(__builtin_amdgcn_exp2f)
    return __builtin_amdgcn_exp2f(x);
#else
    return exp2f(x);
#endif
}

// DPP lane-add at VALU speed (no DS pipe).
template <int CTRL>
__device__ __forceinline__ float dpp_addf(float x) {
    int y = __builtin_amdgcn_update_dpp(0, __float_as_int(x), CTRL, 0xF, 0xF, true);
    return x + __int_as_float(y);
}
template <int GRP>
__device__ __forceinline__ float grp_sum(float p, int lane) {
    p = dpp_addf<0xB1>(p);    // xor 1
    p = dpp_addf<0x4E>(p);    // xor 2
    p = dpp_addf<0x141>(p);   // xor 4 (8-group done)
    if (GRP == 64) {
        p = dpp_addf<0x140>(p);   // xor 8
        p += __int_as_float(__builtin_amdgcn_ds_swizzle(__float_as_int(p), 0x401F)); // xor16
        p += __int_as_float(__builtin_amdgcn_ds_bpermute((lane ^ 32) << 2,
                                                         __float_as_int(p)));        // xor32
    }
    return p;
}

// Broadcast lane ((lane&0x18)|SRC)'s u32 to its 8-lane group (BitMode swizzle).
template <int SRC>
__device__ __forceinline__ u32 bcast8u(u32 x) {
    return (u32)__builtin_amdgcn_ds_swizzle((int)x, 0x18 | (SRC << 5));
}

// ---------------- diagnostic sentinel (fp32 out) ----------------------------
__global__ __launch_bounds__(256) void fill_sentinel(float* __restrict__ out, int n, float val) {
    int i = blockIdx.x * 256 + threadIdx.x;
    if (i < n) out[i] = val;
}

// ---------------- runtime format detection (one wave) -----------------------
__global__ __launch_bounds__(64) void detect_fmt(const u32* __restrict__ xw,
                                                 const int* __restrict__ eraw,
                                                 int* __restrict__ flags) {
    int lane = threadIdx.x;
    u32 e = (xw[lane] >> 7) & 0xffu;
    unsigned long long sane = __ballot(e >= 90u && e <= 141u);
    unsigned long long zodd = __ballot(eraw[1 + 2 * lane] == 0);
    if (lane == 0) {
        flags[0] = (sane == ~0ull) ? 0 : 1;   // 1 = fp32
        flags[1] = (zodd == ~0ull) ? 1 : 0;   // 1 = int64
    }
}

// ---------------- x -> bf16 conversion (once) -------------------------------
__global__ __launch_bounds__(256) void convert_x(const void* __restrict__ X,
                                                 const int* __restrict__ flags,
                                                 u16* __restrict__ xbf, int total) {
    int i = (blockIdx.x * 256 + threadIdx.x) * 8;
    if (i >= total) return;
    if (flags[0]) {
        const float* xf = (const float*)X + i;
        float4 lo = *reinterpret_cast<const float4*>(xf);
        float4 hi = *reinterpret_cast<const float4*>(xf + 4);
        uint4 val = make_uint4(pack2(lo.x, lo.y), pack2(lo.z, lo.w),
                               pack2(hi.x, hi.y), pack2(hi.z, hi.w));
        *reinterpret_cast<uint4*>(xbf + i) = val;
    } else {
        *reinterpret_cast<uint4*>(xbf + i) =
            *reinterpret_cast<const uint4*>((const u16*)X + i);
    }
}

// ---------------- weight transpose+convert: W[K][128] -> Wt[128][K] bf16 ----
struct TPtrs {
    const void* src[8];
    u16*        dst[8];
    int         K[8];
};

__global__ __launch_bounds__(256) void transpose_w(TPtrs P, const int* __restrict__ fmt) {
    int m = blockIdx.x;
    int f = *fmt;
    int K = P.K[m];
    int quarter = (K * 128) >> 2;
    u16* d = P.dst[m];
    int base = blockIdx.y * quarter;
    const float* sf = (const float*)P.src[m];
    const u16*   sb = (const u16*)P.src[m];
    for (int idx = base + threadIdx.x; idx < base + quarter; idx += 256) {
        int k = idx >> 7, n = idx & 127;
        d[n * K + k] = f ? f2bf(sf[idx]) : sb[idx];
    }
}

// ---------------- combined weights: Wqe = Wq (.) We per head ----------------
// L1: Wqe1[i, h*32+d] = sum_{c<16} Wq1[i,16h+c]*We1[d,16h+c]  (h=0..7)
//     -> Wt format split: WtA (cols 0..127 = h<4), WtB (h>=4).
// L2: Wqe2[i, d] = 0.125 * sum_{c<128} Wq2[i,c]*We2[d,c] (d<32; rest 0);
//     the 0.125 bakes the 8x lane-replication of the GRP=64 reduction.
// biases: bqe1[256], bqe2[128] (fp32, bqe2 also x0.125).
// WeP: We packed along d for the attn epilogue:
//     WeP[t*64+l] = { pack(We[2t][2l],We[2t+1][2l]), pack(We[2t][2l+1],We[2t+1][2l+1]) }
struct WqeP {
    const void *Wq1, *We1, *bq1, *Wq2, *We2, *bq2;
    u16 *WtA, *WtB, *Wt2;
    float *bqe1, *bqe2;
    uint2 *WeP1, *WeP2;
};

__global__ __launch_bounds__(256) void make_wqe(WqeP P, const int* __restrict__ flags) {
    int f = flags[0];
    int idx = blockIdx.x * 256 + threadIdx.x;
    if (idx < 32768) {                          // layer-1 weights
        int col = idx >> 7, i = idx & 127;
        int hh = col >> 5, d = col & 31;
        float s = 0.f;
#pragma unroll
        for (int c = 0; c < 16; ++c)
            s += rdv(P.Wq1, i * 128 + hh * 16 + c, f) * rdv(P.We1, d * 128 + hh * 16 + c, f);
        if (col < 128) P.WtA[col * 128 + i] = f2bf(s);
        else           P.WtB[(col - 128) * 128 + i] = f2bf(s);
    } else if (idx < 49152) {                   // layer-2 weights (zero-padded, x0.125)
        int t = idx - 32768;
        int col = t >> 7, i = t & 127;
        float s = 0.f;
        if (col < 32) {
            for (int c = 0; c < 128; ++c)
                s += rdv(P.Wq2, i * 128 + c, f) * rdv(P.We2, col * 128 + c, f);
        }
        P.Wt2[col * 128 + i] = f2bf(s * 0.125f);
    } else if (idx < 49408) {                   // bqe1
        int col = idx - 49152;
        int hh = col >> 5, d = col & 31;
        float s = 0.f;
#pragma unroll
        for (int c = 0; c < 16; ++c)
            s += rdv(P.bq1, hh * 16 + c, f) * rdv(P.We1, d * 128 + hh * 16 + c, f);
        P.bqe1[col] = s;
    } else if (idx < 49536) {                   // bqe2 (x0.125)
        int d = idx - 49408;
        float s = 0.f;
        if (d < 32)
            for (int c = 0; c < 128; ++c)
                s += rdv(P.bq2, c, f) * rdv(P.We2, d * 128 + c, f);
        P.bqe2[d] = s * 0.125f;
    } else if (idx < 50560) {                   // WeP1: 1024 entries
        int ent = idx - 49536;
        int t = ent >> 6, l = ent & 63, c0 = 2 * l;
        u32 xv = pack2(rdv(P.We1, (2 * t) * 128 + c0, f),
                       rdv(P.We1, (2 * t + 1) * 128 + c0, f));
        u32 yv = pack2(rdv(P.We1, (2 * t) * 128 + c0 + 1, f),
                       rdv(P.We1, (2 * t + 1) * 128 + c0 + 1, f));
        P.WeP1[ent] = make_uint2(xv, yv);
    } else if (idx < 51584) {                   // WeP2: 1024 entries
        int ent = idx - 50560;
        int t = ent >> 6, l = ent & 63, c0 = 2 * l;
        u32 xv = pack2(rdv(P.We2, (2 * t) * 128 + c0, f),
                       rdv(P.We2, (2 * t + 1) * 128 + c0, f));
        u32 yv = pack2(rdv(P.We2, (2 * t) * 128 + c0 + 1, f),
                       rdv(P.We2, (2 * t + 1) * 128 + c0 + 1, f));
        P.WeP2[ent] = make_uint2(xv, yv);
    }
}

// ---------------- CSR build (by dst) ----------------------------------------
__global__ __launch_bounds__(256) void count_deg(const int* __restrict__ raw,
                                                 const int* __restrict__ flags,
                                                 int* __restrict__ deg, int E) {
    int e = blockIdx.x * 256 + threadIdx.x;
    if (e < E) {
        int f = flags[1];
        int d = f ? raw[2 * (E + e)] : raw[E + e];
        if ((unsigned)d < (unsigned)NODES) atomicAdd(&deg[d], 1);
    }
}

__device__ __forceinline__ int block_scan256(int v) {
    __shared__ int ws[4];
    int t = threadIdx.x, lane = t & 63, w = t >> 6;
    int x = v;
#pragma unroll
    for (int off = 1; off < 64; off <<= 1) {
        int y = __shfl_up(x, off, 64);
        if (lane >= off) x += y;
    }
    if (lane == 63) ws[w] = x;
    __syncthreads();
#pragma unroll
    for (int j = 0; j < 3; ++j)
        if (j < w) x += ws[j];
    return x;
}

__global__ __launch_bounds__(256) void scan_a(const int* __restrict__ deg,
                                              int* __restrict__ bsum, int n) {
    int i = blockIdx.x * 256 + threadIdx.x;
    int v = (i < n) ? deg[i] : 0;
    int incl = block_scan256(v);
    if (threadIdx.x == 255) bsum[blockIdx.x] = incl;
}

__global__ __launch_bounds__(256) void scan_b(int* __restrict__ bsum, int nb) {
    int t = threadIdx.x;
    int v = (t < nb) ? bsum[t] : 0;
    int incl = block_scan256(v);
    if (t < nb) bsum[t] = incl - v;
}

__global__ __launch_bounds__(256) void scan_c(const int* __restrict__ deg,
                                              const int* __restrict__ bsum,
                                              int* __restrict__ row_ptr,
                                              int* __restrict__ cursor, int n) {
    int b = blockIdx.x;
    int i = b * 256 + threadIdx.x;
    int v = (i < n) ? deg[i] : 0;
    int incl = block_scan256(v) + bsum[b];
    if (i < n) {
        row_ptr[i + 1] = incl;
        cursor[i] = incl - v;
    }
    if (i == 0) row_ptr[0] = 0;
}

__global__ __launch_bounds__(256) void fill_csr(const int* __restrict__ raw,
                                                const int* __restrict__ flags,
                                                int* __restrict__ cursor,
                                                int* __restrict__ srcs,
                                                int* __restrict__ eids, int E) {
    int e = blockIdx.x * 256 + threadIdx.x;
    if (e < E) {
        int f = flags[1];
        int d = f ? raw[2 * (E + e)] : raw[E + e];
        int s = f ? raw[2 * e] : raw[e];
        if ((unsigned)d < (unsigned)NODES && (unsigned)s < (unsigned)NODES) {
            int pos = atomicAdd(&cursor[d], 1);
            if ((unsigned)pos < (unsigned)E) { srcs[pos] = s; eids[pos] = e; }
        }
    }
}

// ---------------- ef gather to CSR order, bf16 (shared by both layers) ------
__global__ __launch_bounds__(256) void gather_ef(const int* __restrict__ eids,
                                                 const void* __restrict__ EF,
                                                 const int* __restrict__ flags,
                                                 u16* __restrict__ EFG, int E) {
    int t = blockIdx.x * 256 + threadIdx.x;
    int pos = t >> 2, seg = t & 3;
    if (pos >= E) return;
    int e = eids[pos];
    uint4 val;
    if (flags[0]) {
        const float* src = (const float*)EF + (size_t)e * 32 + seg * 8;
        float4 lo = *reinterpret_cast<const float4*>(src);
        float4 hi = *reinterpret_cast<const float4*>(src + 4);
        val = make_uint4(pack2(lo.x, lo.y), pack2(lo.z, lo.w),
                         pack2(hi.x, hi.y), pack2(hi.z, hi.w));
    } else {
        val = *reinterpret_cast<const uint4*>((const u16*)EF + (size_t)e * 32 + seg * 8);
    }
    *reinterpret_cast<uint4*>(EFG + (size_t)pos * 32 + seg * 8) = val;
}

// ---------------- GEMM: O[M,128] = A[M,128] @ Wt[128,128]^T + bias ----------
struct GemmSets {
    const u16*  Wt[6];
    const void* bias[6];
    u16*        O[6];
    int         bf32[6];    // 1 = bias is fp32 always, 0 = follow input flags
    int         pitch[6];   // output row pitch in u16 elements
};

__global__ __launch_bounds__(256) void gemm128(
    const u16* __restrict__ A, const int* __restrict__ flags, GemmSets S, int M) {
    constexpr int K = 128;
    constexpr int PAD = K + 8;
    constexpr int KV = K / 8;
    __shared__ u16 Asl[64 * PAD];
    __shared__ u16 Bsl[128 * PAD];

    const u16*  Wt   = S.Wt[blockIdx.y];
    const void* bias = S.bias[blockIdx.y];
    u16*        O    = S.O[blockIdx.y];
    int pitch = S.pitch[blockIdx.y];
    int f = S.bf32[blockIdx.y] ? 1 : flags[0];
    int m0 = blockIdx.x * 64;

    for (int idx = threadIdx.x; idx < 64 * KV; idx += 256) {
        int r = idx / KV, cv = idx % KV;
        int gr = m0 + r;
        uint4 val = make_uint4(0, 0, 0, 0);
        if (gr < M) val = *reinterpret_cast<const uint4*>(A + (size_t)gr * K + cv * 8);
        *reinterpret_cast<uint4*>(&Asl[r * PAD + cv * 8]) = val;
    }
    for (int idx = threadIdx.x; idx < 128 * KV; idx += 256) {
        int r = idx / KV, cv = idx % KV;
        *reinterpret_cast<uint4*>(&Bsl[r * PAD + cv * 8]) =
            *reinterpret_cast<const uint4*>(Wt + r * K + cv * 8);
    }
    __syncthreads();

    int lane = threadIdx.x & 63, wv = threadIdx.x >> 6;
    int l15 = lane & 15;
    int quad = lane >> 4;
    int kq = quad * 8;

    f32x4 b4[8];
#pragma unroll
    for (int nt = 0; nt < 8; ++nt) {
        int col0 = nt * 16 + quad * 4;
        if (bias) {
            if (f) {
                b4[nt] = *reinterpret_cast<const f32x4*>((const float*)bias + col0);
            } else {
                uint2 bu = *reinterpret_cast<const uint2*>((const u16*)bias + col0);
                b4[nt][0] = bflo(bu.x); b4[nt][1] = bfhi(bu.x);
                b4[nt][2] = bflo(bu.y); b4[nt][3] = bfhi(bu.y);
            }
        } else {
            b4[nt][0] = b4[nt][1] = b4[nt][2] = b4[nt][3] = 0.f;
        }
    }

    f32x4 acc[8] = {};
#pragma unroll
    for (int k0 = 0; k0 < K; k0 += 32) {
        bf16x8 xf = *reinterpret_cast<const bf16x8*>(&Asl[(wv * 16 + l15) * PAD + k0 + kq]);
#pragma unroll
        for (int nt = 0; nt < 8; ++nt) {
            bf16x8 wf = *reinterpret_cast<const bf16x8*>(&Bsl[(nt * 16 + l15) * PAD + k0 + kq]);
            acc[nt] = __builtin_amdgcn_mfma_f32_16x16x32_bf16(wf, xf, acc[nt], 0, 0, 0);
        }
    }

    int row = m0 + wv * 16 + l15;
    if (row < M) {
        u16* Orow = O + (size_t)row * pitch;
#pragma unroll
        for (int nt = 0; nt < 8; ++nt) {
            uint2 pk;
            pk.x = pack2(acc[nt][0] + b4[nt][0], acc[nt][1] + b4[nt][1]);
            pk.y = pack2(acc[nt][2] + b4[nt][2], acc[nt][3] + b4[nt][3]);
            *reinterpret_cast<uint2*>(Orow + nt * 16 + quad * 4) = pk;
        }
    }
}

// ---------------- attention: factorized ee, scalar addressing, dot2 ---------
// Per wave = 4 consecutive dst nodes. Lane (h=lane>>3, j=lane&7) owns channels
// 16h+2j..+1 and ef dims 4j..4j+3. beg/end readfirstlane'd -> srcs via s_load,
// kv/ef bases scalar. Score = 3 chained dot2 on packed bf16; scale post-sum
// (exp2(p*s2), L2's /8 baked into qwe2). Exact-8 main loop + masked-4 tail.
// Epilogue: F packed to bf16, bcast8 per group, dot2 vs WeP (packed along d).
template <int HEADS, int F32OUT>
__global__ __launch_bounds__(256) void attn_kernel(
    const int* __restrict__ row_ptr, const int* __restrict__ srcs,
    const u16* __restrict__ Q, const u16* __restrict__ KV,
    const u16* __restrict__ EFG,
    const u16* __restrict__ QWA, const u16* __restrict__ QWB,
    const u16* __restrict__ SK, const uint2* __restrict__ WeP,
    void* __restrict__ OUT, int nn) {
    int wv = threadIdx.x >> 6, lane = threadIdx.x & 63;
    int node0 = (blockIdx.x * 4 + wv) * 4;
    if (node0 >= nn) return;
    int h = lane >> 3, j = lane & 7;
    int c0 = lane * 2;

    const float s2 = (HEADS == 8) ? 0.25f * 1.44269504f
                                  : 0.08838834764831845f * 1.44269504f;
    constexpr int GRP = (HEADS == 8) ? 8 : 64;

    // We packed along d: wD[t] = pairs (We[2t][c0],We[2t+1][c0]) / (..c0+1)
    uint2 wD[16];
#pragma unroll
    for (int t = 0; t < 16; ++t) wD[t] = WeP[t * 64 + lane];

    int nend = (node0 + 4 < nn) ? node0 + 4 : nn;
    for (int node = node0; node < nend; ++node) {
        u32 qb = *reinterpret_cast<const u32*>(Q + (size_t)node * 128 + c0);
        const u16* qp = (HEADS == 8)
            ? ((h < 4 ? QWA : QWB) + (size_t)node * 128 + (h & 3) * 32 + j * 4)
            : (QWA + (size_t)node * 128 + j * 4);
        uint2 qwu = *reinterpret_cast<const uint2*>(qp);

        int beg = __builtin_amdgcn_readfirstlane(row_ptr[node]);
        int end = __builtin_amdgcn_readfirstlane(row_ptr[node + 1]);

        float l_run = 0.f, a0 = 0.f, a1 = 0.f;
        float f0 = 0.f, f1 = 0.f, f2 = 0.f, f3 = 0.f;

        auto edge_step = [&](u32 kbv, u32 vbv, uint2 ebv, bool valid) {
            float p = dot2bf(qb, kbv,
                     dot2bf(qwu.x, ebv.x,
                     dot2bf(qwu.y, ebv.y, 0.f)));
            p = grp_sum<GRP>(p, lane);
            float w = fexp2(p * s2);
            if (!valid) w = 0.f;
            l_run += w;
            a0 = fmaf(w, bflo(vbv), a0);
            a1 = fmaf(w, bfhi(vbv), a1);
            f0 = fmaf(w, bflo(ebv.x), f0); f1 = fmaf(w, bfhi(ebv.x), f1);
            f2 = fmaf(w, bflo(ebv.y), f2); f3 = fmaf(w, bfhi(ebv.y), f3);
        };

        int i = beg;
        for (; i + 8 <= end; i += 8) {          // exact batches, no masking
            u32 kb[8], vb[8]; uint2 eb[8];
#pragma unroll
            for (int t = 0; t < 8; ++t) {
                int s = srcs[i + t];            // uniform -> s_load
                const u16* kp = KV + (size_t)s * 256;
                kb[t] = *reinterpret_cast<const u32*>(kp + c0);
                vb[t] = *reinterpret_cast<const u32*>(kp + 128 + c0);
                eb[t] = *reinterpret_cast<const uint2*>(EFG + (size_t)(i + t) * 32 + j * 4);
            }
#pragma unroll
            for (int t = 0; t < 8; ++t) edge_step(kb[t], vb[t], eb[t], true);
        }
        for (; i < end; i += 4) {               // masked tail, batch 4
            int kleft = end - i;
            u32 kb[4], vb[4]; uint2 eb[4];
#pragma unroll
            for (int t = 0; t < 4; ++t) {
                int idx = (i + t < end) ? i + t : end - 1;
                int s = srcs[idx];
                const u16* kp = KV + (size_t)s * 256;
                kb[t] = *reinterpret_cast<const u32*>(kp + c0);
                vb[t] = *reinterpret_cast<const u32*>(kp + 128 + c0);
                eb[t] = *reinterpret_cast<const uint2*>(EFG + (size_t)idx * 32 + j * 4);
            }
#pragma unroll
            for (int t = 0; t < 4; ++t) edge_step(kb[t], vb[t], eb[t], t < kleft);
        }

        // ---- epilogue: out_ee[c] = sum_d F[d]*We[d][c], packed F + dot2 ----
        u32 Fp0 = pack2(f0, f1), Fp1 = pack2(f2, f3);
        float acc0 = 0.f, acc1 = 0.f;
#define EPI(SRC) do { \
        u32 A = bcast8u<SRC>(Fp0), B = bcast8u<SRC>(Fp1); \
        uint2 w0 = wD[2 * SRC], w1 = wD[2 * SRC + 1]; \
        acc0 = dot2bf(A, w0.x, acc0); acc0 = dot2bf(B, w1.x, acc0); \
        acc1 = dot2bf(A, w0.y, acc1); acc1 = dot2bf(B, w1.y, acc1); \
    } while (0)
        EPI(0); EPI(1); EPI(2); EPI(3); EPI(4); EPI(5); EPI(6); EPI(7);
#undef EPI

        float inv = 1.f / fmaxf(l_run, 1e-16f);
        u32 sb = *reinterpret_cast<const u32*>(SK + (size_t)node * 128 + c0);
        float o0 = fmaxf(fmaf(a0 + acc0, inv, bflo(sb)), 0.f);
        float o1 = fmaxf(fmaf(a1 + acc1, inv, bfhi(sb)), 0.f);
        if (F32OUT) {
            *reinterpret_cast<float2*>((float*)OUT + (size_t)node * 128 + c0) =
                make_float2(o0, o1);
        } else {
            *reinterpret_cast<u32*>((u16*)OUT + (size_t)node * 128 + c0) = pack2(o0, o1);
        }
    }
}

// ---------------------------------------------------------------------------
extern "C" void kernel_launch(void* const* d_in, const int* in_sizes, int n_in,
                              void* d_out, int out_size, void* d_ws, size_t ws_size,
                              hipStream_t stream) {
    const int N = NODES, E = EDGES;
    const void* x  = d_in[0];
    const int*  ei = (const int*)d_in[1];
    const void* ef = d_in[2];
    const void* Wq1 = d_in[3];  const void* bq1 = d_in[4];
    const void* Wk1 = d_in[5];  const void* bk1 = d_in[6];
    const void* Wv1 = d_in[7];  const void* bv1 = d_in[8];
    const void* We1 = d_in[9];
    const void* Ws1 = d_in[10]; const void* bs1 = d_in[11];
    const void* Wq2 = d_in[12]; const void* bq2 = d_in[13];
    const void* Wk2 = d_in[14]; const void* bk2 = d_in[15];
    const void* Wv2 = d_in[16]; const void* bv2 = d_in[17];
    const void* We2 = d_in[18];
    const void* Ws2 = d_in[19]; const void* bs2 = d_in[20];

    char* ws = (char*)d_ws;
    size_t off = 0;
    auto carve = [&](size_t bytes) -> void* {
        void* p = ws + off;
        off += (bytes + 255) & ~(size_t)255;
        return p;
    };

    u16* WtQ1 = (u16*)carve(128 * 128 * 2);
    u16* WtK1 = (u16*)carve(128 * 128 * 2);
    u16* WtV1 = (u16*)carve(128 * 128 * 2);
    u16* WtS1 = (u16*)carve(128 * 128 * 2);
    u16* WtQ2 = (u16*)carve(128 * 128 * 2);
    u16* WtK2 = (u16*)carve(128 * 128 * 2);
    u16* WtV2 = (u16*)carve(128 * 128 * 2);
    u16* WtS2 = (u16*)carve(128 * 128 * 2);
    u16* WtqA = (u16*)carve(128 * 128 * 2);
    u16* WtqB = (u16*)carve(128 * 128 * 2);
    u16* Wtq2 = (u16*)carve(128 * 128 * 2);
    float* bqe1 = (float*)carve(256 * 4);
    float* bqe2 = (float*)carve(128 * 4);
    uint2* WeP1 = (uint2*)carve(1024 * 8);
    uint2* WeP2 = (uint2*)carve(1024 * 8);
    int* flags   = (int*)carve(256);
    int* deg     = (int*)carve((size_t)N * 4);
    int* bsum    = (int*)carve((size_t)NB196 * 4);
    int* row_ptr = (int*)carve((size_t)(N + 1) * 4);
    int* cursor  = (int*)carve((size_t)N * 4);
    int* srcs    = (int*)carve((size_t)E * 4);
    int* eids    = (int*)carve((size_t)E * 4);
    u16* xbf  = (u16*)carve((size_t)N * 128 * 2);
    u16* q    = (u16*)carve((size_t)N * 128 * 2);
    u16* kv   = (u16*)carve((size_t)N * 256 * 2);   // k rows [0:128], v rows [128:256]
    u16* sk   = (u16*)carve((size_t)N * 128 * 2);
    u16* h    = (u16*)carve((size_t)N * 128 * 2);
    u16* qweA = (u16*)carve((size_t)N * 128 * 2);
    u16* qweB = (u16*)carve((size_t)N * 128 * 2);
    u16* qwe2 = (u16*)carve((size_t)N * 128 * 2);
    u16* efg  = (u16*)carve((size_t)E * 32 * 2);
    const size_t REQ = off;   // ~146 MB

    if (ws_size < REQ) {
        hipLaunchKernelGGL(fill_sentinel, dim3((out_size + 255) / 256), dim3(256), 0, stream,
                           (float*)d_out, out_size, 16.0f * (float)(ws_size >> 20));
        return;
    }

    hipLaunchKernelGGL(detect_fmt, dim3(1), dim3(64), 0, stream, (const u32*)x, ei, flags);

    hipLaunchKernelGGL(convert_x, dim3((N * 128 / 8 + 255) / 256), dim3(256), 0, stream,
                       x, flags, xbf, N * 128);

    TPtrs tp;
    tp.src[0] = Wq1; tp.dst[0] = WtQ1; tp.K[0] = 128;
    tp.src[1] = Wk1; tp.dst[1] = WtK1; tp.K[1] = 128;
    tp.src[2] = Wv1; tp.dst[2] = WtV1; tp.K[2] = 128;
    tp.src[3] = Ws1; tp.dst[3] = WtS1; tp.K[3] = 128;
    tp.src[4] = Wq2; tp.dst[4] = WtQ2; tp.K[4] = 128;
    tp.src[5] = Wk2; tp.dst[5] = WtK2; tp.K[5] = 128;
    tp.src[6] = Wv2; tp.dst[6] = WtV2; tp.K[6] = 128;
    tp.src[7] = Ws2; tp.dst[7] = WtS2; tp.K[7] = 128;
    hipLaunchKernelGGL(transpose_w, dim3(8, 4), dim3(256), 0, stream, tp, flags);

    WqeP wp;
    wp.Wq1 = Wq1; wp.We1 = We1; wp.bq1 = bq1;
    wp.Wq2 = Wq2; wp.We2 = We2; wp.bq2 = bq2;
    wp.WtA = WtqA; wp.WtB = WtqB; wp.Wt2 = Wtq2;
    wp.bqe1 = bqe1; wp.bqe2 = bqe2;
    wp.WeP1 = WeP1; wp.WeP2 = WeP2;
    hipLaunchKernelGGL(make_wqe, dim3(202), dim3(256), 0, stream, wp, flags);

    (void)hipMemsetAsync(deg, 0, (size_t)N * 4, stream);
    hipLaunchKernelGGL(count_deg, dim3((E + 255) / 256), dim3(256), 0, stream, ei, flags, deg, E);
    hipLaunchKernelGGL(scan_a, dim3(NB196), dim3(256), 0, stream, deg, bsum, N);
    hipLaunchKernelGGL(scan_b, dim3(1), dim3(256), 0, stream, bsum, NB196);
    hipLaunchKernelGGL(scan_c, dim3(NB196), dim3(256), 0, stream, deg, bsum, row_ptr, cursor, N);
    hipLaunchKernelGGL(fill_csr, dim3((E + 255) / 256), dim3(256), 0, stream, ei, flags, cursor,
                       srcs, eids, E);

    hipLaunchKernelGGL(gather_ef, dim3(E * 4 / 256), dim3(256), 0, stream,
                       eids, ef, flags, efg, E);

    const int gN = (N + 63) / 64;    // 782
    const int gA = (N + 15) / 16;    // 3125 (4 waves x 4 nodes per block)

    // layer 1: q,k,v,sk + qWe (two halves)
    {
        GemmSets S;
        S.Wt[0] = WtQ1; S.bias[0] = bq1;  S.O[0] = q;        S.bf32[0] = 0; S.pitch[0] = 128;
        S.Wt[1] = WtK1; S.bias[1] = bk1;  S.O[1] = kv;       S.bf32[1] = 0; S.pitch[1] = 256;
        S.Wt[2] = WtV1; S.bias[2] = bv1;  S.O[2] = kv + 128; S.bf32[2] = 0; S.pitch[2] = 256;
        S.Wt[3] = WtS1; S.bias[3] = bs1;  S.O[3] = sk;       S.bf32[3] = 0; S.pitch[3] = 128;
        S.Wt[4] = WtqA; S.bias[4] = bqe1;       S.O[4] = qweA; S.bf32[4] = 1; S.pitch[4] = 128;
        S.Wt[5] = WtqB; S.bias[5] = bqe1 + 128; S.O[5] = qweB; S.bf32[5] = 1; S.pitch[5] = 128;
        hipLaunchKernelGGL(gemm128, dim3(gN, 6), dim3(256), 0, stream, xbf, flags, S, N);
    }
    hipLaunchKernelGGL((attn_kernel<8, 0>), dim3(gA), dim3(256), 0, stream,
                       row_ptr, srcs, q, kv, efg, qweA, qweB, sk, WeP1, (void*)h, N);

    // layer 2: q,k,v,sk + qWe2
    {
        GemmSets S;
        S.Wt[0] = WtQ2; S.bias[0] = bq2;  S.O[0] = q;        S.bf32[0] = 0; S.pitch[0] = 128;
        S.Wt[1] = WtK2; S.bias[1] = bk2;  S.O[1] = kv;       S.bf32[1] = 0; S.pitch[1] = 256;
        S.Wt[2] = WtV2; S.bias[2] = bv2;  S.O[2] = kv + 128; S.bf32[2] = 0; S.pitch[2] = 256;
        S.Wt[3] = WtS2; S.bias[3] = bs2;  S.O[3] = sk;       S.bf32[3] = 0; S.pitch[3] = 128;
        S.Wt[4] = Wtq2; S.bias[4] = bqe2; S.O[4] = qwe2;     S.bf32[4] = 1; S.pitch[4] = 128;
        S.Wt[5] = Wtq2; S.bias[5] = bqe2; S.O[5] = qwe2;     S.bf32[5] = 1; S.pitch[5] = 128;
        hipLaunchKernelGGL(gemm128, dim3(gN, 5), dim3(256), 0, stream, h, flags, S, N);
    }
    hipLaunchKernelGGL((attn_kernel<1, 1>), dim3(gA), dim3(256), 0, stream,
                       row_ptr, srcs, q, kv, efg, qwe2, qwe2, sk, WeP2, d_out, N);
}

// Round 4
// 429.770 us; speedup vs baseline: 1.2719x; 1.0301x over previous
//
#include <hip/hip_runtime.h>

// GraphAttentionEmbedding: 2x TransformerConv (PyG) on MI355X (gfx950).
// N=50000, E=400000, IN=128, H1=8*16=128, OUT=128, EDIM=32.
// PROVEN: fp32 inputs (runtime-detected), fp32 output; internal bf16+fp32 acc.
// R17 (factorized ee, scalar addressing, dot2): attn 59us but occupancy fell
// 46->30% (4 nodes/wave = only 12500 waves on an 8192-slot machine) ->
// latency-bound, 2.5 TB/s vs R14's 3.27 at same traffic.
// R18: 1 node/wave (50000 waves) to restore latency hiding; softmax scale
// folded into gemm epilogue (oscale) -> w=exp2(p), no per-edge mul; prep
// kernels merged (convert+count, transpose+wqe) to cut launch count.

using u16 = unsigned short;
using u32 = unsigned int;

#define NODES 50000
#define EDGES 400000
#define NB196 196   // ceil(50000/256)

typedef __attribute__((ext_vector_type(8))) short bf16x8;
typedef __attribute__((ext_vector_type(4))) float f32x4;

__device__ __forceinline__ float bflo(u32 u) { return __uint_as_float(u << 16); }
__device__ __forceinline__ float bfhi(u32 u) { return __uint_as_float(u & 0xffff0000u); }
__device__ __forceinline__ u16 f2bf(float f) {
    u32 u = __float_as_uint(f);
    u += 0x7fffu + ((u >> 16) & 1u);   // RNE
    return (u16)(u >> 16);
}
__device__ __forceinline__ u32 pack2(float a, float b) {
    return (u32)f2bf(a) | ((u32)f2bf(b) << 16);
}
__device__ __forceinline__ float rdv(const void* p, int i, int f) {
    return f ? ((const float*)p)[i]
             : __uint_as_float(((u32) reinterpret_cast<const u16*>(p)[i]) << 16);
}

// dot2 on packed bf16 pairs: p = a.lo*b.lo + a.hi*b.hi + c
#if __has_builtin(__builtin_amdgcn_fdot2_f32_bf16)
typedef __attribute__((ext_vector_type(2))) __bf16 bf2;
__device__ __forceinline__ float dot2bf(u32 a, u32 b, float c) {
    return __builtin_amdgcn_fdot2_f32_bf16(__builtin_bit_cast(bf2, a),
                                           __builtin_bit_cast(bf2, b), c, false);
}
#else
__device__ __forceinline__ float dot2bf(u32 a, u32 b, float c) {
    return fmaf(bflo(a), bflo(b), fmaf(bfhi(a), bfhi(b), c));
}
#endif

__device__ __forceinline__ float fexp2(float x) {
#if __has_builtin(__builtin_amdgcn_exp2f)
    return __builtin_amdgcn_exp2f(x);
#else
    return exp2f(x);
#endif
}

// DPP lane-add at VALU speed (no DS pipe).
template <int CTRL>
__device__ __forceinline__ float dpp_addf(float x) {
    int y = __builtin_amdgcn_update_dpp(0, __float_as_int(x), CTRL, 0xF, 0xF, true);
    return x + __int_as_float(y);
}
template <int GRP>
__device__ __forceinline__ float grp_sum(float p, int lane) {
    p = dpp_addf<0xB1>(p);    // xor 1
    p = dpp_addf<0x4E>(p);    // xor 2
    p = dpp_addf<0x141>(p);   // xor 4 (8-group done)
    if (GRP == 64) {
        p = dpp_addf<0x140>(p);   // xor 8
        p += __int_as_float(__builtin_amdgcn_ds_swizzle(__float_as_int(p), 0x401F)); // xor16
        p += __int_as_float(__builtin_amdgcn_ds_bpermute((lane ^ 32) << 2,
                                                         __float_as_int(p)));        // xor32
    }
    return p;
}

// Broadcast lane ((lane&0x18)|SRC)'s u32 to its 8-lane group (BitMode swizzle).
template <int SRC>
__device__ __forceinline__ u32 bcast8u(u32 x) {
    return (u32)__builtin_amdgcn_ds_swizzle((int)x, 0x18 | (SRC << 5));
}

// ---------------- diagnostic sentinel (fp32 out) ----------------------------
__global__ __launch_bounds__(256) void fill_sentinel(float* __restrict__ out, int n, float val) {
    int i = blockIdx.x * 256 + threadIdx.x;
    if (i < n) out[i] = val;
}

// ---------------- runtime format detection (one wave) -----------------------
__global__ __launch_bounds__(64) void detect_fmt(const u32* __restrict__ xw,
                                                 const int* __restrict__ eraw,
                                                 int* __restrict__ flags) {
    int lane = threadIdx.x;
    u32 e = (xw[lane] >> 7) & 0xffu;
    unsigned long long sane = __ballot(e >= 90u && e <= 141u);
    unsigned long long zodd = __ballot(eraw[1 + 2 * lane] == 0);
    if (lane == 0) {
        flags[0] = (sane == ~0ull) ? 0 : 1;   // 1 = fp32
        flags[1] = (zodd == ~0ull) ? 1 : 0;   // 1 = int64
    }
}

// ---------------- merged: x->bf16 convert (blocks [0,CXB)) + deg count ------
#define CXB 3125    // 50000*128/8/256
#define CDB 1563    // ceil(400000/256)
__global__ __launch_bounds__(256) void convert_count(
    const void* __restrict__ X, const int* __restrict__ raw,
    const int* __restrict__ flags, u16* __restrict__ xbf,
    int* __restrict__ deg, int total, int E) {
    int b = blockIdx.x;
    if (b < CXB) {
        int i = (b * 256 + threadIdx.x) * 8;
        if (i >= total) return;
        if (flags[0]) {
            const float* xf = (const float*)X + i;
            float4 lo = *reinterpret_cast<const float4*>(xf);
            float4 hi = *reinterpret_cast<const float4*>(xf + 4);
            uint4 val = make_uint4(pack2(lo.x, lo.y), pack2(lo.z, lo.w),
                                   pack2(hi.x, hi.y), pack2(hi.z, hi.w));
            *reinterpret_cast<uint4*>(xbf + i) = val;
        } else {
            *reinterpret_cast<uint4*>(xbf + i) =
                *reinterpret_cast<const uint4*>((const u16*)X + i);
        }
    } else {
        int e = (b - CXB) * 256 + threadIdx.x;
        if (e < E) {
            int f = flags[1];
            int d = f ? raw[2 * (E + e)] : raw[E + e];
            if ((unsigned)d < (unsigned)NODES) atomicAdd(&deg[d], 1);
        }
    }
}

// ---------------- merged weight prep: transpose (blocks [0,32)) + wqe -------
// transpose: W[K][128] -> Wt[128][K] bf16.
// Wqe L1: Wqe1[i, h*32+d] = sum_{c<16} Wq1[i,16h+c]*We1[d,16h+c] -> WtA/WtB.
// Wqe L2: Wqe2[i, d] = 0.125 * sum_{c<128} Wq2[i,c]*We2[d,c] (d<32; rest 0);
//     0.125 bakes the 8x lane-replication of the GRP=64 reduction.
// biases: bqe1[256], bqe2[128] (fp32, bqe2 x0.125).
// WeP: We packed along d for the attn epilogue:
//     WeP[t*64+l] = { pack(We[2t][2l],We[2t+1][2l]), pack(We[2t][2l+1],We[2t+1][2l+1]) }
struct TPtrs {
    const void* src[8];
    u16*        dst[8];
    int         K[8];
};
struct WqeP {
    const void *Wq1, *We1, *bq1, *Wq2, *We2, *bq2;
    u16 *WtA, *WtB, *Wt2;
    float *bqe1, *bqe2;
    uint2 *WeP1, *WeP2;
};

__global__ __launch_bounds__(256) void prep_w(TPtrs P, WqeP Q, const int* __restrict__ flags) {
    int f = flags[0];
    int b = blockIdx.x;
    if (b < 32) {
        int m = b >> 2;
        int K = P.K[m];
        int quarter = (K * 128) >> 2;
        u16* d = P.dst[m];
        int base = (b & 3) * quarter;
        const float* sf = (const float*)P.src[m];
        const u16*   sb = (const u16*)P.src[m];
        for (int idx = base + threadIdx.x; idx < base + quarter; idx += 256) {
            int k = idx >> 7, n = idx & 127;
            d[n * K + k] = f ? f2bf(sf[idx]) : sb[idx];
        }
        return;
    }
    int idx = (b - 32) * 256 + threadIdx.x;
    if (idx < 32768) {                          // layer-1 combined weights
        int col = idx >> 7, i = idx & 127;
        int hh = col >> 5, d = col & 31;
        float s = 0.f;
#pragma unroll
        for (int c = 0; c < 16; ++c)
            s += rdv(Q.Wq1, i * 128 + hh * 16 + c, f) * rdv(Q.We1, d * 128 + hh * 16 + c, f);
        if (col < 128) Q.WtA[col * 128 + i] = f2bf(s);
        else           Q.WtB[(col - 128) * 128 + i] = f2bf(s);
    } else if (idx < 49152) {                   // layer-2 weights (zero-padded, x0.125)
        int t = idx - 32768;
        int col = t >> 7, i = t & 127;
        float s = 0.f;
        if (col < 32) {
            for (int c = 0; c < 128; ++c)
                s += rdv(Q.Wq2, i * 128 + c, f) * rdv(Q.We2, col * 128 + c, f);
        }
        Q.Wt2[col * 128 + i] = f2bf(s * 0.125f);
    } else if (idx < 49408) {                   // bqe1
        int col = idx - 49152;
        int hh = col >> 5, d = col & 31;
        float s = 0.f;
#pragma unroll
        for (int c = 0; c < 16; ++c)
            s += rdv(Q.bq1, hh * 16 + c, f) * rdv(Q.We1, d * 128 + hh * 16 + c, f);
        Q.bqe1[col] = s;
    } else if (idx < 49536) {                   // bqe2 (x0.125)
        int d = idx - 49408;
        float s = 0.f;
        if (d < 32)
            for (int c = 0; c < 128; ++c)
                s += rdv(Q.bq2, c, f) * rdv(Q.We2, d * 128 + c, f);
        Q.bqe2[d] = s * 0.125f;
    } else if (idx < 50560) {                   // WeP1: 1024 entries
        int ent = idx - 49536;
        int t = ent >> 6, l = ent & 63, c0 = 2 * l;
        u32 xv = pack2(rdv(Q.We1, (2 * t) * 128 + c0, f),
                       rdv(Q.We1, (2 * t + 1) * 128 + c0, f));
        u32 yv = pack2(rdv(Q.We1, (2 * t) * 128 + c0 + 1, f),
                       rdv(Q.We1, (2 * t + 1) * 128 + c0 + 1, f));
        Q.WeP1[ent] = make_uint2(xv, yv);
    } else if (idx < 51584) {                   // WeP2: 1024 entries
        int ent = idx - 50560;
        int t = ent >> 6, l = ent & 63, c0 = 2 * l;
        u32 xv = pack2(rdv(Q.We2, (2 * t) * 128 + c0, f),
                       rdv(Q.We2, (2 * t + 1) * 128 + c0, f));
        u32 yv = pack2(rdv(Q.We2, (2 * t) * 128 + c0 + 1, f),
                       rdv(Q.We2, (2 * t + 1) * 128 + c0 + 1, f));
        Q.WeP2[ent] = make_uint2(xv, yv);
    }
}

// ---------------- CSR build (by dst) ----------------------------------------
__device__ __forceinline__ int block_scan256(int v) {
    __shared__ int ws[4];
    int t = threadIdx.x, lane = t & 63, w = t >> 6;
    int x = v;
#pragma unroll
    for (int off = 1; off < 64; off <<= 1) {
        int y = __shfl_up(x, off, 64);
        if (lane >= off) x += y;
    }
    if (lane == 63) ws[w] = x;
    __syncthreads();
#pragma unroll
    for (int j = 0; j < 3; ++j)
        if (j < w) x += ws[j];
    return x;
}

__global__ __launch_bounds__(256) void scan_a(const int* __restrict__ deg,
                                              int* __restrict__ bsum, int n) {
    int i = blockIdx.x * 256 + threadIdx.x;
    int v = (i < n) ? deg[i] : 0;
    int incl = block_scan256(v);
    if (threadIdx.x == 255) bsum[blockIdx.x] = incl;
}

__global__ __launch_bounds__(256) void scan_b(int* __restrict__ bsum, int nb) {
    int t = threadIdx.x;
    int v = (t < nb) ? bsum[t] : 0;
    int incl = block_scan256(v);
    if (t < nb) bsum[t] = incl - v;
}

__global__ __launch_bounds__(256) void scan_c(const int* __restrict__ deg,
                                              const int* __restrict__ bsum,
                                              int* __restrict__ row_ptr,
                                              int* __restrict__ cursor, int n) {
    int b = blockIdx.x;
    int i = b * 256 + threadIdx.x;
    int v = (i < n) ? deg[i] : 0;
    int incl = block_scan256(v) + bsum[b];
    if (i < n) {
        row_ptr[i + 1] = incl;
        cursor[i] = incl - v;
    }
    if (i == 0) row_ptr[0] = 0;
}

__global__ __launch_bounds__(256) void fill_csr(const int* __restrict__ raw,
                                                const int* __restrict__ flags,
                                                int* __restrict__ cursor,
                                                int* __restrict__ srcs,
                                                int* __restrict__ eids, int E) {
    int e = blockIdx.x * 256 + threadIdx.x;
    if (e < E) {
        int f = flags[1];
        int d = f ? raw[2 * (E + e)] : raw[E + e];
        int s = f ? raw[2 * e] : raw[e];
        if ((unsigned)d < (unsigned)NODES && (unsigned)s < (unsigned)NODES) {
            int pos = atomicAdd(&cursor[d], 1);
            if ((unsigned)pos < (unsigned)E) { srcs[pos] = s; eids[pos] = e; }
        }
    }
}

// ---------------- ef gather to CSR order, bf16 (shared by both layers) ------
__global__ __launch_bounds__(256) void gather_ef(const int* __restrict__ eids,
                                                 const void* __restrict__ EF,
                                                 const int* __restrict__ flags,
                                                 u16* __restrict__ EFG, int E) {
    int t = blockIdx.x * 256 + threadIdx.x;
    int pos = t >> 2, seg = t & 3;
    if (pos >= E) return;
    int e = eids[pos];
    uint4 val;
    if (flags[0]) {
        const float* src = (const float*)EF + (size_t)e * 32 + seg * 8;
        float4 lo = *reinterpret_cast<const float4*>(src);
        float4 hi = *reinterpret_cast<const float4*>(src + 4);
        val = make_uint4(pack2(lo.x, lo.y), pack2(lo.z, lo.w),
                         pack2(hi.x, hi.y), pack2(hi.z, hi.w));
    } else {
        val = *reinterpret_cast<const uint4*>((const u16*)EF + (size_t)e * 32 + seg * 8);
    }
    *reinterpret_cast<uint4*>(EFG + (size_t)pos * 32 + seg * 8) = val;
}

// ---------------- GEMM: O[M,128] = (A[M,128] @ Wt^T + bias) * oscale --------
// oscale folds the softmax 1/sqrt(C)*log2(e) into q / qwe outputs so attn
// uses exp2(p) directly with no per-edge multiply.
struct GemmSets {
    const u16*  Wt[6];
    const void* bias[6];
    u16*        O[6];
    int         bf32[6];    // 1 = bias is fp32 always, 0 = follow input flags
    int         pitch[6];   // output row pitch in u16 elements
    float       oscale[6];  // output scale (1.0 for k/v/sk)
};

__global__ __launch_bounds__(256) void gemm128(
    const u16* __restrict__ A, const int* __restrict__ flags, GemmSets S, int M) {
    constexpr int K = 128;
    constexpr int PAD = K + 8;
    constexpr int KV = K / 8;
    __shared__ u16 Asl[64 * PAD];
    __shared__ u16 Bsl[128 * PAD];

    const u16*  Wt   = S.Wt[blockIdx.y];
    const void* bias = S.bias[blockIdx.y];
    u16*        O    = S.O[blockIdx.y];
    int pitch = S.pitch[blockIdx.y];
    float os  = S.oscale[blockIdx.y];
    int f = S.bf32[blockIdx.y] ? 1 : flags[0];
    int m0 = blockIdx.x * 64;

    for (int idx = threadIdx.x; idx < 64 * KV; idx += 256) {
        int r = idx / KV, cv = idx % KV;
        int gr = m0 + r;
        uint4 val = make_uint4(0, 0, 0, 0);
        if (gr < M) val = *reinterpret_cast<const uint4*>(A + (size_t)gr * K + cv * 8);
        *reinterpret_cast<uint4*>(&Asl[r * PAD + cv * 8]) = val;
    }
    for (int idx = threadIdx.x; idx < 128 * KV; idx += 256) {
        int r = idx / KV, cv = idx % KV;
        *reinterpret_cast<uint4*>(&Bsl[r * PAD + cv * 8]) =
            *reinterpret_cast<const uint4*>(Wt + r * K + cv * 8);
    }
    __syncthreads();

    int lane = threadIdx.x & 63, wv = threadIdx.x >> 6;
    int l15 = lane & 15;
    int quad = lane >> 4;
    int kq = quad * 8;

    f32x4 b4[8];
#pragma unroll
    for (int nt = 0; nt < 8; ++nt) {
        int col0 = nt * 16 + quad * 4;
        if (bias) {
            if (f) {
                b4[nt] = *reinterpret_cast<const f32x4*>((const float*)bias + col0);
            } else {
                uint2 bu = *reinterpret_cast<const uint2*>((const u16*)bias + col0);
                b4[nt][0] = bflo(bu.x); b4[nt][1] = bfhi(bu.x);
                b4[nt][2] = bflo(bu.y); b4[nt][3] = bfhi(bu.y);
            }
        } else {
            b4[nt][0] = b4[nt][1] = b4[nt][2] = b4[nt][3] = 0.f;
        }
    }

    f32x4 acc[8] = {};
#pragma unroll
    for (int k0 = 0; k0 < K; k0 += 32) {
        bf16x8 xf = *reinterpret_cast<const bf16x8*>(&Asl[(wv * 16 + l15) * PAD + k0 + kq]);
#pragma unroll
        for (int nt = 0; nt < 8; ++nt) {
            bf16x8 wf = *reinterpret_cast<const bf16x8*>(&Bsl[(nt * 16 + l15) * PAD + k0 + kq]);
            acc[nt] = __builtin_amdgcn_mfma_f32_16x16x32_bf16(wf, xf, acc[nt], 0, 0, 0);
        }
    }

    int row = m0 + wv * 16 + l15;
    if (row < M) {
        u16* Orow = O + (size_t)row * pitch;
#pragma unroll
        for (int nt = 0; nt < 8; ++nt) {
            uint2 pk;
            pk.x = pack2((acc[nt][0] + b4[nt][0]) * os, (acc[nt][1] + b4[nt][1]) * os);
            pk.y = pack2((acc[nt][2] + b4[nt][2]) * os, (acc[nt][3] + b4[nt][3]) * os);
            *reinterpret_cast<uint2*>(Orow + nt * 16 + quad * 4) = pk;
        }
    }
}

// ---------------- attention: factorized ee, 1 node/wave, dot2 ---------------
// Per wave = one dst node (50000 waves -> full latency hiding). Lane
// (h=lane>>3, j=lane&7) owns channels 16h+2j..+1 and ef dims 4j..4j+3.
// Score p = q.k + qw.ef (scale pre-folded via gemm oscale) -> w = exp2(p).
// Exact-8 main loop + masked-4 tail. Epilogue: F packed bf16, bcast8 per
// group, dot2 vs WeP (packed along d, loaded post-loop: short live range).
template <int HEADS, int F32OUT>
__global__ __launch_bounds__(256) void attn_kernel(
    const int* __restrict__ row_ptr, const int* __restrict__ srcs,
    const u16* __restrict__ Q, const u16* __restrict__ KV,
    const u16* __restrict__ EFG,
    const u16* __restrict__ QWA, const u16* __restrict__ QWB,
    const u16* __restrict__ SK, const uint2* __restrict__ WeP,
    void* __restrict__ OUT, int nn) {
    int wv = threadIdx.x >> 6, lane = threadIdx.x & 63;
    int node = blockIdx.x * 4 + wv;
    if (node >= nn) return;
    int h = lane >> 3, j = lane & 7;
    int c0 = lane * 2;
    constexpr int GRP = (HEADS == 8) ? 8 : 64;

    u32 qb = *reinterpret_cast<const u32*>(Q + (size_t)node * 128 + c0);
    const u16* qp = (HEADS == 8)
        ? ((h < 4 ? QWA : QWB) + (size_t)node * 128 + (h & 3) * 32 + j * 4)
        : (QWA + (size_t)node * 128 + j * 4);
    uint2 qwu = *reinterpret_cast<const uint2*>(qp);

    int beg = __builtin_amdgcn_readfirstlane(row_ptr[node]);
    int end = __builtin_amdgcn_readfirstlane(row_ptr[node + 1]);

    float l_run = 0.f, a0 = 0.f, a1 = 0.f;
    float f0 = 0.f, f1 = 0.f, f2 = 0.f, f3 = 0.f;

    auto edge_step = [&](u32 kbv, u32 vbv, uint2 ebv, bool valid) {
        float p = dot2bf(qb, kbv,
                 dot2bf(qwu.x, ebv.x,
                 dot2bf(qwu.y, ebv.y, 0.f)));
        p = grp_sum<GRP>(p, lane);
        float w = fexp2(p);
        if (!valid) w = 0.f;
        l_run += w;
        a0 = fmaf(w, bflo(vbv), a0);
        a1 = fmaf(w, bfhi(vbv), a1);
        f0 = fmaf(w, bflo(ebv.x), f0); f1 = fmaf(w, bfhi(ebv.x), f1);
        f2 = fmaf(w, bflo(ebv.y), f2); f3 = fmaf(w, bfhi(ebv.y), f3);
    };

    int i = beg;
    for (; i + 8 <= end; i += 8) {          // exact batches, no masking
        u32 kb[8], vb[8]; uint2 eb[8];
#pragma unroll
        for (int t = 0; t < 8; ++t) {
            int s = srcs[i + t];            // uniform -> s_load
            const u16* kp = KV + (size_t)s * 256;
            kb[t] = *reinterpret_cast<const u32*>(kp + c0);
            vb[t] = *reinterpret_cast<const u32*>(kp + 128 + c0);
            eb[t] = *reinterpret_cast<const uint2*>(EFG + (size_t)(i + t) * 32 + j * 4);
        }
#pragma unroll
        for (int t = 0; t < 8; ++t) edge_step(kb[t], vb[t], eb[t], true);
    }
    for (; i < end; i += 4) {               // masked tail, batch 4
        int kleft = end - i;
        u32 kb[4], vb[4]; uint2 eb[4];
#pragma unroll
        for (int t = 0; t < 4; ++t) {
            int idx = (i + t < end) ? i + t : end - 1;
            int s = srcs[idx];
            const u16* kp = KV + (size_t)s * 256;
            kb[t] = *reinterpret_cast<const u32*>(kp + c0);
            vb[t] = *reinterpret_cast<const u32*>(kp + 128 + c0);
            eb[t] = *reinterpret_cast<const uint2*>(EFG + (size_t)idx * 32 + j * 4);
        }
#pragma unroll
        for (int t = 0; t < 4; ++t) edge_step(kb[t], vb[t], eb[t], t < kleft);
    }

    // ---- epilogue: out_ee[c] = sum_d F[d]*We[d][c], packed F + dot2 --------
    u32 Fp0 = pack2(f0, f1), Fp1 = pack2(f2, f3);
    float acc0 = 0.f, acc1 = 0.f;
#define EPI(SRC) do { \
        u32 A = bcast8u<SRC>(Fp0), B = bcast8u<SRC>(Fp1); \
        uint2 w0 = WeP[(2 * SRC) * 64 + lane]; \
        uint2 w1 = WeP[(2 * SRC + 1) * 64 + lane]; \
        acc0 = dot2bf(A, w0.x, acc0); acc0 = dot2bf(B, w1.x, acc0); \
        acc1 = dot2bf(A, w0.y, acc1); acc1 = dot2bf(B, w1.y, acc1); \
    } while (0)
    EPI(0); EPI(1); EPI(2); EPI(3); EPI(4); EPI(5); EPI(6); EPI(7);
#undef EPI

    float inv = 1.f / fmaxf(l_run, 1e-16f);
    u32 sb = *reinterpret_cast<const u32*>(SK + (size_t)node * 128 + c0);
    float o0 = fmaxf(fmaf(a0 + acc0, inv, bflo(sb)), 0.f);
    float o1 = fmaxf(fmaf(a1 + acc1, inv, bfhi(sb)), 0.f);
    if (F32OUT) {
        *reinterpret_cast<float2*>((float*)OUT + (size_t)node * 128 + c0) =
            make_float2(o0, o1);
    } else {
        *reinterpret_cast<u32*>((u16*)OUT + (size_t)node * 128 + c0) = pack2(o0, o1);
    }
}

// ---------------------------------------------------------------------------
extern "C" void kernel_launch(void* const* d_in, const int* in_sizes, int n_in,
                              void* d_out, int out_size, void* d_ws, size_t ws_size,
                              hipStream_t stream) {
    const int N = NODES, E = EDGES;
    const void* x  = d_in[0];
    const int*  ei = (const int*)d_in[1];
    const void* ef = d_in[2];
    const void* Wq1 = d_in[3];  const void* bq1 = d_in[4];
    const void* Wk1 = d_in[5];  const void* bk1 = d_in[6];
    const void* Wv1 = d_in[7];  const void* bv1 = d_in[8];
    const void* We1 = d_in[9];
    const void* Ws1 = d_in[10]; const void* bs1 = d_in[11];
    const void* Wq2 = d_in[12]; const void* bq2 = d_in[13];
    const void* Wk2 = d_in[14]; const void* bk2 = d_in[15];
    const void* Wv2 = d_in[16]; const void* bv2 = d_in[17];
    const void* We2 = d_in[18];
    const void* Ws2 = d_in[19]; const void* bs2 = d_in[20];

    char* ws = (char*)d_ws;
    size_t off = 0;
    auto carve = [&](size_t bytes) -> void* {
        void* p = ws + off;
        off += (bytes + 255) & ~(size_t)255;
        return p;
    };

    u16* WtQ1 = (u16*)carve(128 * 128 * 2);
    u16* WtK1 = (u16*)carve(128 * 128 * 2);
    u16* WtV1 = (u16*)carve(128 * 128 * 2);
    u16* WtS1 = (u16*)carve(128 * 128 * 2);
    u16* WtQ2 = (u16*)carve(128 * 128 * 2);
    u16* WtK2 = (u16*)carve(128 * 128 * 2);
    u16* WtV2 = (u16*)carve(128 * 128 * 2);
    u16* WtS2 = (u16*)carve(128 * 128 * 2);
    u16* WtqA = (u16*)carve(128 * 128 * 2);
    u16* WtqB = (u16*)carve(128 * 128 * 2);
    u16* Wtq2 = (u16*)carve(128 * 128 * 2);
    float* bqe1 = (float*)carve(256 * 4);
    float* bqe2 = (float*)carve(128 * 4);
    uint2* WeP1 = (uint2*)carve(1024 * 8);
    uint2* WeP2 = (uint2*)carve(1024 * 8);
    int* flags   = (int*)carve(256);
    int* deg     = (int*)carve((size_t)N * 4);
    int* bsum    = (int*)carve((size_t)NB196 * 4);
    int* row_ptr = (int*)carve((size_t)(N + 1) * 4);
    int* cursor  = (int*)carve((size_t)N * 4);
    int* srcs    = (int*)carve((size_t)E * 4);
    int* eids    = (int*)carve((size_t)E * 4);
    u16* xbf  = (u16*)carve((size_t)N * 128 * 2);
    u16* q    = (u16*)carve((size_t)N * 128 * 2);
    u16* kv   = (u16*)carve((size_t)N * 256 * 2);   // k rows [0:128], v rows [128:256]
    u16* sk   = (u16*)carve((size_t)N * 128 * 2);
    u16* h    = (u16*)carve((size_t)N * 128 * 2);
    u16* qweA = (u16*)carve((size_t)N * 128 * 2);
    u16* qweB = (u16*)carve((size_t)N * 128 * 2);
    u16* qwe2 = (u16*)carve((size_t)N * 128 * 2);
    u16* efg  = (u16*)carve((size_t)E * 32 * 2);
    const size_t REQ = off;   // ~146 MB

    if (ws_size < REQ) {
        hipLaunchKernelGGL(fill_sentinel, dim3((out_size + 255) / 256), dim3(256), 0, stream,
                           (float*)d_out, out_size, 16.0f * (float)(ws_size >> 20));
        return;
    }

    const float s2_1 = 0.25f * 1.44269504f;               // 1/sqrt(16) * log2(e)
    const float s2_2 = 0.08838834764831845f * 1.44269504f; // 1/sqrt(128) * log2(e)

    hipLaunchKernelGGL(detect_fmt, dim3(1), dim3(64), 0, stream, (const u32*)x, ei, flags);

    (void)hipMemsetAsync(deg, 0, (size_t)N * 4, stream);
    hipLaunchKernelGGL(convert_count, dim3(CXB + CDB), dim3(256), 0, stream,
                       x, ei, flags, xbf, deg, N * 128, E);

    TPtrs tp;
    tp.src[0] = Wq1; tp.dst[0] = WtQ1; tp.K[0] = 128;
    tp.src[1] = Wk1; tp.dst[1] = WtK1; tp.K[1] = 128;
    tp.src[2] = Wv1; tp.dst[2] = WtV1; tp.K[2] = 128;
    tp.src[3] = Ws1; tp.dst[3] = WtS1; tp.K[3] = 128;
    tp.src[4] = Wq2; tp.dst[4] = WtQ2; tp.K[4] = 128;
    tp.src[5] = Wk2; tp.dst[5] = WtK2; tp.K[5] = 128;
    tp.src[6] = Wv2; tp.dst[6] = WtV2; tp.K[6] = 128;
    tp.src[7] = Ws2; tp.dst[7] = WtS2; tp.K[7] = 128;
    WqeP wp;
    wp.Wq1 = Wq1; wp.We1 = We1; wp.bq1 = bq1;
    wp.Wq2 = Wq2; wp.We2 = We2; wp.bq2 = bq2;
    wp.WtA = WtqA; wp.WtB = WtqB; wp.Wt2 = Wtq2;
    wp.bqe1 = bqe1; wp.bqe2 = bqe2;
    wp.WeP1 = WeP1; wp.WeP2 = WeP2;
    hipLaunchKernelGGL(prep_w, dim3(32 + 202), dim3(256), 0, stream, tp, wp, flags);

    hipLaunchKernelGGL(scan_a, dim3(NB196), dim3(256), 0, stream, deg, bsum, N);
    hipLaunchKernelGGL(scan_b, dim3(1), dim3(256), 0, stream, bsum, NB196);
    hipLaunchKernelGGL(scan_c, dim3(NB196), dim3(256), 0, stream, deg, bsum, row_ptr, cursor, N);
    hipLaunchKernelGGL(fill_csr, dim3((E + 255) / 256), dim3(256), 0, stream, ei, flags, cursor,
                       srcs, eids, E);

    hipLaunchKernelGGL(gather_ef, dim3(E * 4 / 256), dim3(256), 0, stream,
                       eids, ef, flags, efg, E);

    const int gN = (N + 63) / 64;    // 782
    const int gA = (N + 3) / 4;      // 12500 (1 node per wave)

    // layer 1: q,k,v,sk + qWe (two halves); q & qwe pre-scaled by s2_1
    {
        GemmSets S;
        S.Wt[0] = WtQ1; S.bias[0] = bq1;  S.O[0] = q;        S.bf32[0] = 0; S.pitch[0] = 128; S.oscale[0] = s2_1;
        S.Wt[1] = WtK1; S.bias[1] = bk1;  S.O[1] = kv;       S.bf32[1] = 0; S.pitch[1] = 256; S.oscale[1] = 1.f;
        S.Wt[2] = WtV1; S.bias[2] = bv1;  S.O[2] = kv + 128; S.bf32[2] = 0; S.pitch[2] = 256; S.oscale[2] = 1.f;
        S.Wt[3] = WtS1; S.bias[3] = bs1;  S.O[3] = sk;       S.bf32[3] = 0; S.pitch[3] = 128; S.oscale[3] = 1.f;
        S.Wt[4] = WtqA; S.bias[4] = bqe1;       S.O[4] = qweA; S.bf32[4] = 1; S.pitch[4] = 128; S.oscale[4] = s2_1;
        S.Wt[5] = WtqB; S.bias[5] = bqe1 + 128; S.O[5] = qweB; S.bf32[5] = 1; S.pitch[5] = 128; S.oscale[5] = s2_1;
        hipLaunchKernelGGL(gemm128, dim3(gN, 6), dim3(256), 0, stream, xbf, flags, S, N);
    }
    hipLaunchKernelGGL((attn_kernel<8, 0>), dim3(gA), dim3(256), 0, stream,
                       row_ptr, srcs, q, kv, efg, qweA, qweB, sk, WeP1, (void*)h, N);

    // layer 2: q,k,v,sk + qWe2; q & qwe2 pre-scaled by s2_2 (x0.125 in wqe)
    {
        GemmSets S;
        S.Wt[0] = WtQ2; S.bias[0] = bq2;  S.O[0] = q;        S.bf32[0] = 0; S.pitch[0] = 128; S.oscale[0] = s2_2;
        S.Wt[1] = WtK2; S.bias[1] = bk2;  S.O[1] = kv;       S.bf32[1] = 0; S.pitch[1] = 256; S.oscale[1] = 1.f;
        S.Wt[2] = WtV2; S.bias[2] = bv2;  S.O[2] = kv + 128; S.bf32[2] = 0; S.pitch[2] = 256; S.oscale[2] = 1.f;
        S.Wt[3] = WtS2; S.bias[3] = bs2;  S.O[3] = sk;       S.bf32[3] = 0; S.pitch[3] = 128; S.oscale[3] = 1.f;
        S.Wt[4] = Wtq2; S.bias[4] = bqe2; S.O[4] = qwe2;     S.bf32[4] = 1; S.pitch[4] = 128; S.oscale[4] = s2_2;
        S.Wt[5] = Wtq2; S.bias[5] = bqe2; S.O[5] = qwe2;     S.bf32[5] = 1; S.pitch[5] = 128; S.oscale[5] = s2_2;
        hipLaunchKernelGGL(gemm128, dim3(gN, 5), dim3(256), 0, stream, h, flags, S, N);
    }
    hipLaunchKernelGGL((attn_kernel<1, 1>), dim3(gA), dim3(256), 0, stream,
                       row_ptr, srcs, q, kv, efg, qwe2, qwe2, sk, WeP2, d_out, N);
}